// Round 26
// baseline (90.434 us; speedup 1.0000x reference)
//
#include <hip/hip_runtime.h>
#include <hip/hip_fp8.h>
#include <cstdint>
#include <cstddef>

using short8 = __attribute__((ext_vector_type(8))) short;
using f32x4  = __attribute__((ext_vector_type(4))) float;
using bfraw  = unsigned short;

// ---------------- helpers ----------------
__device__ __forceinline__ bfraw f2b(float f){
  unsigned int u = __builtin_bit_cast(unsigned int, f);
  u += 0x7FFFu + ((u >> 16) & 1u);            // round-to-nearest-even
  return (bfraw)(u >> 16);
}
__device__ __forceinline__ float b2f(bfraw h){
  unsigned int u = ((unsigned int)h) << 16;
  return __builtin_bit_cast(float, u);
}
__device__ __forceinline__ unsigned char f2f8(float f){   // OCP e4m3fn
  __hip_fp8_e4m3 t(f);
  return (unsigned char)t.__x;
}
__device__ __forceinline__ float srelu(float x){ // smooth_relu, d=0.1
  float r = fmaxf(x, 0.0f);
  if (r < 0.1f){ float r2 = r * r; return (0.2f * r2 * r - r2 * r2) * 500.0f; }
  return x - 0.05f;
}
__device__ __forceinline__ float softplusf(float x){
  return (x > 15.0f) ? x : log1pf(expf(x));
}
__device__ __forceinline__ void gload16(const void* g, void* s){
  __builtin_amdgcn_global_load_lds((const __attribute__((address_space(1))) void*)g,
                                   (__attribute__((address_space(3))) void*)s, 16, 0, 0);
}
// counted vmcnt wait (T4)
template<int N> __device__ __forceinline__ void wait_vm(){
  if constexpr (N == 0)      asm volatile("s_waitcnt vmcnt(0)" ::: "memory");
  else if constexpr (N == 2) asm volatile("s_waitcnt vmcnt(2)" ::: "memory");
  else if constexpr (N == 3) asm volatile("s_waitcnt vmcnt(3)" ::: "memory");
  else                       asm volatile("s_waitcnt vmcnt(4)" ::: "memory");
}
__device__ __forceinline__ void block_barrier(){
  __builtin_amdgcn_s_barrier();
  asm volatile("" ::: "memory");
}

// ---------------- workspace layout (bytes) ----------------
constexpr size_t OFF_STATEB = 0;               // 4096*2048 bf16 = 16MB
constexpr size_t OFF_STATE8 = 16777216;        // 4096*2048 fp8 = 8MB
constexpr size_t OFF_HUB    = 25165824;        // 4096*1024 fp8 = 4MB
constexpr size_t OFF_PT     = 29360128;        // 1024*1024 bf16 = 2MB
constexpr size_t OFF_PTEIG  = 31457280;        // 1024*1024 bf16 = 2MB
constexpr size_t OFF_LM8    = 33554432;        // 1024*1024 fp8 = 1MB
constexpr size_t OFF_W1F8   = 34603008;        // 512*2048 fp8 = 1MB
constexpr size_t OFF_ICWB   = 35651584;        // 128*2048 bf16 = 0.5MB
constexpr size_t OFF_W28    = 36175872;        // 512*512 fp8 = 256KB
constexpr size_t OFF_W38    = 36438016;        // 2048*512 fp8 = 1MB
constexpr size_t OFF_H18    = 37486592;        // 4096*512 fp8 = 2MB
constexpr size_t OFF_H28    = 39583744;        // 4096*512 fp8 = 2MB
constexpr size_t OFF_Z1F    = 41680896;        // 4096*64 f32 = 1MB
constexpr size_t OFF_Z2PRE  = 42729472;        // 4096*64 f32 = 1MB
constexpr size_t OFF_SPU0   = 43778048;        // 64*64 f32
constexpr size_t OFF_SPU1   = 43794432;        // 64 f32
constexpr size_t OFF_Z0     = 43794688;        // 1 f32 (padded)
constexpr size_t OFF_SU1    = 43794944;        // 512 f32
constexpr size_t OFF_SV1    = 43796992;        // 512 f32
constexpr size_t OFF_U0     = 43799040;        // 4096 f32
constexpr size_t OFF_V0     = 43815424;        // 4096 f32
constexpr size_t OFF_RD     = 43831808;        // 4096 f32 (rowdot = icW2 . state_row)
constexpr size_t OFF_RS     = 43848192;        // 4096 f32 (rowss = ||state_row||^2)
constexpr size_t OFF_SPU0T  = 43864576;        // 64*64 f32 (spU0 transposed: [j][n])

// ---------------- merged prep (identical to R25) ----------------
__global__ __launch_bounds__(256) void prep_all(const float* __restrict__ W1,
    const float* __restrict__ icW0, const float* __restrict__ icW1,
    const float* __restrict__ W2, const float* __restrict__ W3,
    const float* __restrict__ P, const float* __restrict__ tptr,
    const float* __restrict__ icU0, const float* __restrict__ icU1,
    const float* __restrict__ icb0, const float* __restrict__ icb1, const float* __restrict__ icb2,
    const float* __restrict__ state, const float* __restrict__ icW2,
    unsigned char* __restrict__ w1f8, bfraw* __restrict__ icwb,
    unsigned char* __restrict__ w28, unsigned char* __restrict__ w3f8,
    bfraw* __restrict__ PT, bfraw* __restrict__ PTeig,
    float* __restrict__ su1, float* __restrict__ sv1,
    float* __restrict__ spU0, float* __restrict__ spU0T,
    float* __restrict__ spU1, float* __restrict__ z0out,
    bfraw* __restrict__ stateb, unsigned char* __restrict__ state8, unsigned char* __restrict__ hub8,
    float* __restrict__ u0a, float* __restrict__ v0a,
    float* __restrict__ rowdot, float* __restrict__ rowss){
  __shared__ float smem[4288];
  const int b = blockIdx.x;
  const int t = threadIdx.x;
  if (b < 2560){
    const int i4 = (b * 256 + t) * 4;
    if (i4 >= 1048576 && i4 < 1310720){
      const float* src = (i4 < 1179648) ? icW0 : icW1;
      const int off = (i4 < 1179648) ? (i4 - 1048576) : (i4 - 1179648);
      const int dsto = i4 - 1048576;
      float4 v = *reinterpret_cast<const float4*>(src + off);
      ushort4 o;
      o.x = f2b(v.x); o.y = f2b(v.y); o.z = f2b(v.z); o.w = f2b(v.w);
      *reinterpret_cast<ushort4*>(icwb + dsto) = o;
    } else {
      const float* src; unsigned char* dst; int off;
      if (i4 < 1048576)      { src = W1; dst = w1f8; off = i4; }
      else if (i4 < 1572864) { src = W2; dst = w28;  off = i4 - 1310720; }
      else                   { src = W3; dst = w3f8; off = i4 - 1572864; }
      float4 v = *reinterpret_cast<const float4*>(src + off);
      uchar4 o;
      o.x = f2f8(v.x); o.y = f2f8(v.y); o.z = f2f8(v.z); o.w = f2f8(v.w);
      *reinterpret_cast<uchar4*>(dst + off) = o;
    }
  } else if (b < 3584){
    float (*tile)[33] = (float(*)[33])smem;
    const int idx = b - 2560;
    const int bi = idx >> 5, bj = idx & 31;
    const int tx = t & 31, ty = t >> 5;
    #pragma unroll
    for (int r = 0; r < 4; ++r){
      const int k = bj * 32 + ty + r * 8;
      const int i = bi * 32 + tx;
      tile[ty + r * 8][tx] = P[(size_t)k * 1024 + i];
    }
    __syncthreads();
    const float s = 2.0f * sinf(tptr[0]);
    #pragma unroll
    for (int r = 0; r < 4; ++r){
      const int i = bi * 32 + ty + r * 8;
      const int k = bj * 32 + tx;
      const float p = tile[tx][ty + r * 8];
      const float e = (k == 0) ? 0.0f : ((k <= 511) ? (1.0f + s) : (1.0f - s));
      PT[(size_t)i * 1024 + k] = f2b(p);
      PTeig[(size_t)i * 1024 + k] = f2b(e * p);
    }
  } else if (b < 4096){
    const int n = b - 3584;
    float a = 0.0f, bb = 0.0f;
    for (int j = t; j < 1024; j += 256) a += W1[(size_t)n * 2048 + j];
    for (int j = t; j < 1024; j += 256) bb += W1[(size_t)n * 2048 + 1024 + j];
    #pragma unroll
    for (int o = 32; o > 0; o >>= 1){ a += __shfl_down(a, o, 64); bb += __shfl_down(bb, o, 64); }
    if ((t & 63) == 0){ smem[t >> 6] = a; smem[4 + (t >> 6)] = bb; }
    __syncthreads();
    if (t == 0){
      su1[n] = smem[0] + smem[1] + smem[2] + smem[3];
      sv1[n] = smem[4] + smem[5] + smem[6] + smem[7];
    }
  } else if (b == 4096){
    float* sp  = smem;
    float* sp1 = smem + 4096;
    float* a0  = smem + 4160;
    float* a1  = smem + 4224;
    #pragma unroll
    for (int i = 0; i < 16; ++i){
      const int idx = i * 256 + t;
      const float v = softplusf(icU0[idx]);
      sp[idx] = v;
      spU0[idx] = v;
      spU0T[(idx & 63) * 64 + (idx >> 6)] = v;   // transposed copy [j][n]
    }
    if (t < 64){
      const float v1 = softplusf(icU1[t]);
      sp1[t] = v1;
      spU1[t] = v1;
      a0[t] = srelu(icb0[t]);
    }
    __syncthreads();
    {
      const int n = t >> 2, q = t & 3;
      float sAcc = 0.0f;
      #pragma unroll
      for (int j = 0; j < 16; ++j) sAcc += sp[n * 64 + q * 16 + j] * a0[q * 16 + j];
      sAcc += __shfl_down(sAcc, 2, 64);
      sAcc += __shfl_down(sAcc, 1, 64);
      if (q == 0) a1[n] = srelu(sAcc + icb1[n]);
    }
    __syncthreads();
    if (t < 64){
      float v = sp1[t] * a1[t];
      #pragma unroll
      for (int o = 32; o > 0; o >>= 1) v += __shfl_down(v, o, 64);
      if (t == 0) z0out[0] = srelu(v + icb2[0]);
    }
  } else {
    const int row = b - 4097;
    const float* srow = state + (size_t)row * 2048;
    float4 u4 = *reinterpret_cast<const float4*>(srow + t * 4);
    float4 v4 = *reinterpret_cast<const float4*>(srow + 1024 + t * 4);
    float4 wu = *reinterpret_cast<const float4*>(icW2 + t * 4);
    float4 wv = *reinterpret_cast<const float4*>(icW2 + 1024 + t * 4);
    float us[4] = {u4.x, u4.y, u4.z, u4.w};
    float vs[4] = {v4.x, v4.y, v4.z, v4.w};
    float wus[4] = {wu.x, wu.y, wu.z, wu.w};
    float wvs[4] = {wv.x, wv.y, wv.z, wv.w};
    uchar4 h8, s8u, s8v;
    unsigned char* hp = reinterpret_cast<unsigned char*>(&h8);
    unsigned char* su = reinterpret_cast<unsigned char*>(&s8u);
    unsigned char* sv = reinterpret_cast<unsigned char*>(&s8v);
    float d = 0.0f, ss = 0.0f;
    #pragma unroll
    for (int i = 0; i < 4; ++i){
      const int j = t * 4 + i;
      const float u = us[i], v = vs[i];
      stateb[(size_t)row * 2048 + j] = f2b(u);
      stateb[(size_t)row * 2048 + 1024 + j] = f2b(v);
      su[i] = f2f8(u);
      sv[i] = f2f8(v);
      hp[i] = f2f8(1.0f / (1.0f + expf(-10.0f * u)));
      d  = fmaf(wus[i], u, fmaf(wvs[i], v, d));
      ss = fmaf(u, u, fmaf(v, v, ss));
    }
    *reinterpret_cast<uchar4*>(state8 + (size_t)row * 2048 + t * 4) = s8u;
    *reinterpret_cast<uchar4*>(state8 + (size_t)row * 2048 + 1024 + t * 4) = s8v;
    *reinterpret_cast<uchar4*>(hub8 + (size_t)row * 1024 + t * 4) = h8;
    #pragma unroll
    for (int o = 32; o > 0; o >>= 1){ d += __shfl_down(d, o, 64); ss += __shfl_down(ss, o, 64); }
    if ((t & 63) == 0){ smem[t >> 6] = d; smem[4 + (t >> 6)] = ss; }
    __syncthreads();
    if (t == 0){
      rowdot[row] = smem[0] + smem[1] + smem[2] + smem[3];
      rowss[row]  = smem[4] + smem[5] + smem[6] + smem[7];
      u0a[row] = srow[0]; v0a[row] = srow[1024];
    }
  }
}

// ---------------- merged mid (Lm bf16 + z bf16) + h1 (fp8) in ONE dispatch, 640 blocks ----------------
__global__ __launch_bounds__(512)
void gemm_midh1(const bfraw* __restrict__ pteig, const bfraw* __restrict__ pt,
                unsigned char* __restrict__ lm8,
                const bfraw* __restrict__ stateb, const bfraw* __restrict__ icwb,
                const float* __restrict__ icb0, const float* __restrict__ icb1,
                float* __restrict__ z1f, float* __restrict__ z2pre,
                const unsigned char* __restrict__ state8, const unsigned char* __restrict__ w1f8,
                const float* __restrict__ b1, unsigned char* __restrict__ h18,
                const float* __restrict__ u0a, const float* __restrict__ v0a,
                const float* __restrict__ su1, const float* __restrict__ sv1)
{
  __shared__ char ldsRaw[73728];     // 72KB union
  const int blk = blockIdx.x;
  const int tid = threadIdx.x;
  const int w  = tid >> 6;
  const int l  = tid & 63;
  const int lr = l & 15;
  const int q  = l >> 4;

  if (blk < 384){
    bfraw* lA = (bfraw*)ldsRaw;
    bfraw* lB = (bfraw*)(ldsRaw + 24576);
    const bool isLm = (blk < 256);
    const bfraw* A; const bfraw* B; int K, bm, bn;
    if (isLm){ A = pteig; B = pt; K = 1024; bm = blk >> 4; bn = blk & 15; }
    else     { const int i = blk - 256; A = stateb; B = icwb; K = 2048; bm = i >> 1; bn = i & 1; }
    const int wr = w >> 2;
    const int wc = w & 3;
    f32x4 acc[2] = {};
    const int nt = K >> 6;
    auto stage = [&](int buf, int k0){
      const int r = tid >> 3;
      const int kc = (tid & 7) ^ (r & 7);
      gload16(A + (size_t)(bm * 64 + r) * K + k0 + kc * 8, &lA[(size_t)buf * 4096 + (size_t)(w * 64) * 8]);
      gload16(B + (size_t)(bn * 64 + r) * K + k0 + kc * 8, &lB[(size_t)buf * 4096 + (size_t)(w * 64) * 8]);
    };
    stage(0, 0);
    stage(1, 64);
    for (int t = 0; t < nt; ++t){
      const int cur = t % 3;
      if (t == nt - 1) wait_vm<0>(); else wait_vm<2>();
      block_barrier();
      short8 aF[2][2], bF[2];
      #pragma unroll
      for (int kh = 0; kh < 2; ++kh){
        const int kch = (kh * 4 + q) ^ (lr & 7);
        #pragma unroll
        for (int m = 0; m < 2; ++m){
          const int R = wr * 32 + m * 16 + lr;
          aF[kh][m] = *reinterpret_cast<const short8*>(&lA[(size_t)cur * 4096 + (size_t)R * 64 + kch * 8]);
        }
        const int R = wc * 16 + lr;
        bF[kh] = *reinterpret_cast<const short8*>(&lB[(size_t)cur * 4096 + (size_t)R * 64 + kch * 8]);
      }
      if (t + 2 < nt) stage((t + 2) % 3, (t + 2) * 64);
      #pragma unroll
      for (int kh = 0; kh < 2; ++kh)
        #pragma unroll
        for (int m = 0; m < 2; ++m)
          acc[m] = __builtin_amdgcn_mfma_f32_16x16x32_bf16(aF[kh][m], bF[kh], acc[m], 0, 0, 0);
    }
    #pragma unroll
    for (int m = 0; m < 2; ++m){
      #pragma unroll
      for (int r = 0; r < 4; ++r){
        const int row = bm * 64 + (w >> 2) * 32 + m * 16 + q * 4 + r;
        const int c64 = (w & 3) * 16 + lr;
        const float v = acc[m][r];
        if (isLm){
          lm8[(size_t)row * 1024 + bn * 64 + c64] = f2f8(v);
        } else if (bn == 0){
          z1f[(size_t)row * 64 + c64] = srelu(v + icb0[c64]);
        } else {
          z2pre[(size_t)row * 64 + c64] = v + icb1[c64];
        }
      }
    }
  } else {
    unsigned char* lA = (unsigned char*)ldsRaw;
    unsigned char* lB = (unsigned char*)(ldsRaw + 24576);
    const int i = blk - 384;
    const int bm = i >> 2;
    const int bn = i & 3;
    const int wr = w >> 2;
    const int wc = w & 3;
    constexpr int K = 2048;
    f32x4 acc[2][2] = {};
    const int nt = K >> 7;
    auto stage = [&](int buf, int k0){
      {
        const int c = tid;
        const int r = c >> 3;
        const int kc = (c & 7) ^ (r & 7);
        gload16(state8 + (size_t)(bm * 64 + r) * K + k0 + kc * 16, &lA[(size_t)buf * 8192 + (size_t)(w * 64) * 16]);
      }
      #pragma unroll
      for (int j = 0; j < 2; ++j){
        const int c = j * 512 + tid;
        const int r = c >> 3;
        const int kc = (c & 7) ^ (r & 7);
        gload16(w1f8 + (size_t)(bn * 128 + r) * K + k0 + kc * 16, &lB[(size_t)buf * 16384 + (size_t)(j * 512 + w * 64) * 16]);
      }
    };
    stage(0, 0);
    stage(1, 128);
    for (int t = 0; t < nt; ++t){
      const int cur = t % 3;
      if (t == nt - 1) wait_vm<0>(); else wait_vm<3>();
      block_barrier();
      long long aF[4][2], bF[4][2];
      #pragma unroll
      for (int kh = 0; kh < 4; ++kh){
        const int ko = kh * 32 + q * 8;
        const int ch = (ko >> 4) ^ (lr & 7);
        const int bo = ko & 15;
        #pragma unroll
        for (int m = 0; m < 2; ++m){
          const int R = wr * 32 + m * 16 + lr;
          aF[kh][m] = *reinterpret_cast<const long long*>(&lA[(size_t)cur * 8192 + (size_t)R * 128 + ch * 16 + bo]);
        }
        #pragma unroll
        for (int n = 0; n < 2; ++n){
          const int R = wc * 32 + n * 16 + lr;
          bF[kh][n] = *reinterpret_cast<const long long*>(&lB[(size_t)cur * 16384 + (size_t)R * 128 + ch * 16 + bo]);
        }
      }
      if (t + 2 < nt) stage((t + 2) % 3, (t + 2) * 128);
      #pragma unroll
      for (int kh = 0; kh < 4; ++kh)
        #pragma unroll
        for (int m = 0; m < 2; ++m)
          #pragma unroll
          for (int n = 0; n < 2; ++n)
            acc[m][n] = __builtin_amdgcn_mfma_f32_16x16x32_fp8_fp8(aF[kh][m], bF[kh][n], acc[m][n], 0, 0, 0);
    }
    #pragma unroll
    for (int m = 0; m < 2; ++m){
      #pragma unroll
      for (int n = 0; n < 2; ++n){
        #pragma unroll
        for (int r = 0; r < 4; ++r){
          const int row = bm * 64 + wr * 32 + m * 16 + q * 4 + r;
          const int col = bn * 128 + wc * 32 + n * 16 + lr;
          const float h = acc[m][n][r] - u0a[row] * su1[col] - v0a[row] * sv1[col] + b1[col];
          h18[(size_t)row * 512 + col] = f2f8(tanhf(h));
        }
      }
    }
  }
}

// ---------------- h2 = tanh(h1 @ W2^T + b2) -> fp8 ----------------
__global__ __launch_bounds__(512)
void gemm_h2(const unsigned char* __restrict__ A, const unsigned char* __restrict__ B,
             const float* __restrict__ bias, unsigned char* __restrict__ outf8)
{
  constexpr int N = 512, K = 512;
  __shared__ unsigned char lA[3][64 * 128];
  __shared__ unsigned char lB[3][128 * 128];
  const int tid = threadIdx.x;
  const int w  = tid >> 6;
  const int l  = tid & 63;
  const int wr = w >> 2;
  const int wc = w & 3;
  const int bm = blockIdx.x;
  const int bn = blockIdx.y;
  const int lr = l & 15;
  const int q  = l >> 4;
  f32x4 acc[2][2] = {};
  const int nt = K >> 7;
  auto stage = [&](int buf, int k0){
    {
      const int c = tid;
      const int r = c >> 3;
      const int kc = (c & 7) ^ (r & 7);
      gload16(A + (size_t)(bm * 64 + r) * K + k0 + kc * 16, &lA[buf][(size_t)(w * 64) * 16]);
    }
    #pragma unroll
    for (int j = 0; j < 2; ++j){
      const int c = j * 512 + tid;
      const int r = c >> 3;
      const int kc = (c & 7) ^ (r & 7);
      gload16(B + (size_t)(bn * 128 + r) * K + k0 + kc * 16, &lB[buf][(size_t)(j * 512 + w * 64) * 16]);
    }
  };
  stage(0, 0);
  stage(1, 128);
  for (int t = 0; t < nt; ++t){
    const int cur = t % 3;
    if (t == nt - 1) wait_vm<0>(); else wait_vm<3>();
    block_barrier();
    long long aF[4][2], bF[4][2];
    #pragma unroll
    for (int kh = 0; kh < 4; ++kh){
      const int ko = kh * 32 + q * 8;
      const int ch = (ko >> 4) ^ (lr & 7);
      const int bo = ko & 15;
      #pragma unroll
      for (int m = 0; m < 2; ++m){
        const int R = wr * 32 + m * 16 + lr;
        aF[kh][m] = *reinterpret_cast<const long long*>(&lA[cur][(size_t)R * 128 + ch * 16 + bo]);
      }
      #pragma unroll
      for (int n = 0; n < 2; ++n){
        const int R = wc * 32 + n * 16 + lr;
        bF[kh][n] = *reinterpret_cast<const long long*>(&lB[cur][(size_t)R * 128 + ch * 16 + bo]);
      }
    }
    if (t + 2 < nt) stage((t + 2) % 3, (t + 2) * 128);
    #pragma unroll
    for (int kh = 0; kh < 4; ++kh)
      #pragma unroll
      for (int m = 0; m < 2; ++m)
        #pragma unroll
        for (int n = 0; n < 2; ++n)
          acc[m][n] = __builtin_amdgcn_mfma_f32_16x16x32_fp8_fp8(aF[kh][m], bF[kh][n], acc[m][n], 0, 0, 0);
  }
  #pragma unroll
  for (int m = 0; m < 2; ++m){
    #pragma unroll
    for (int n = 0; n < 2; ++n){
      #pragma unroll
      for (int r = 0; r < 4; ++r){
        const int row = bm * 64 + wr * 32 + m * 16 + q * 4 + r;
        const int col = bn * 128 + wc * 32 + n * 16 + lr;
        outf8[(size_t)row * N + col] = f2f8(tanhf(acc[m][n][r] + bias[col]));
      }
    }
  }
}

// ---------------- merged out + v2 (R25 + phase-2 BK=256 mega-tiles, 4 barrier phases) ----------------
__global__ __launch_bounds__(512, 4)
void gemm_outv2(const unsigned char* __restrict__ hub8, const unsigned char* __restrict__ lm8,
                const unsigned char* __restrict__ h2b8, const unsigned char* __restrict__ w3f8,
                const bfraw* __restrict__ stateb, const float* __restrict__ b3,
                const float* __restrict__ u0a, const float* __restrict__ v0a,
                const float* __restrict__ rowdot, const float* __restrict__ rowss,
                const float* __restrict__ z1f, const float* __restrict__ z2pre,
                const float* __restrict__ spU0T, const float* __restrict__ spU1,
                const float* __restrict__ z0p, const float* __restrict__ icb2,
                float* __restrict__ out)
{
  __shared__ char ldsRaw[33280];   // phase1: 24KB; phase2: A 2x8KB + B 2x8KB = 32KB; v2 z1s at 32768
  const int blk = blockIdx.x;
  const int tid = threadIdx.x;

  if (blk >= 1024){
    // ----- v2 role: tiny — z2 matvec (coalesced spU0T) + combine -----
    float* z1s = (float*)(ldsRaw + 32768);
    const int row = blk - 1024;
    if (tid < 64) z1s[tid] = z1f[(size_t)row * 64 + tid];
    __syncthreads();
    if (tid < 64){
      float acc2 = z2pre[(size_t)row * 64 + tid];
      #pragma unroll 8
      for (int j = 0; j < 64; ++j) acc2 += spU0T[j * 64 + tid] * z1s[j];
      float dd = spU1[tid] * srelu(acc2);
      #pragma unroll
      for (int o = 32; o > 0; o >>= 1) dd += __shfl_down(dd, o, 64);
      if (tid == 0){
        const float D = dd + rowdot[row];
        const float z3 = srelu(D + icb2[0]);
        out[(size_t)row * 2049 + 2048] = srelu(z3 - z0p[0]) + 0.001f * rowss[row];
      }
    }
    return;
  }

  // ----- gemm role: TM=64 + XCD-aware remap (R25) -----
  unsigned char* base = (unsigned char*)ldsRaw;
  const int w  = tid >> 6;
  const int l  = tid & 63;
  const int wr = w >> 2;          // 0..1 (row halves of 64)
  const int wc = w & 3;           // 0..3
  const int xcd = blk & 7;
  const int ii  = blk >> 3;       // 0..127
  const int bm  = xcd * 8 + (ii >> 4);   // 0..63
  const int bn  = ii & 15;               // 0..15
  const int lr = l & 15;
  const int q  = l >> 4;

  const unsigned char* Au  = h2b8 + (size_t)(bm * 64) * 512;
  const unsigned char* Bwl = w3f8 + (size_t)(bn * 64) * 512;
  const unsigned char* Bwh = w3f8 + (size_t)(1024 + bn * 64) * 512;
  const unsigned char* Ah  = hub8 + (size_t)(bm * 64) * 1024;
  const unsigned char* Bl  = lm8  + (size_t)(bn * 64) * 1024;

  f32x4 acc2[2] = {};   // un lo
  f32x4 acc3[2] = {};   // un hi

  // ----- phase 1: un combined (K=512, 4 tiles of BK=128, single-buffer; R23-verified) -----
  {
    unsigned char* lA   = base;            // 8KB
    unsigned char* lBlo = base + 8192;     // 8KB
    unsigned char* lBhi = base + 16384;    // 8KB
    for (int t = 0; t < 4; ++t){
      const int k0 = t * 128;
      const int r = tid >> 3;
      const int kc = (tid & 7) ^ (r & 7);
      gload16(Au  + (size_t)r * 512 + k0 + kc * 16, &lA  [(size_t)(w * 64) * 16]);
      gload16(Bwl + (size_t)r * 512 + k0 + kc * 16, &lBlo[(size_t)(w * 64) * 16]);
      gload16(Bwh + (size_t)r * 512 + k0 + kc * 16, &lBhi[(size_t)(w * 64) * 16]);
      __syncthreads();
      #pragma unroll
      for (int kh = 0; kh < 4; ++kh){
        const int ko = kh * 32 + q * 8;
        const int ch = (ko >> 4) ^ (lr & 7);
        const int bo = ko & 15;
        long long aF[2], bL, bH;
        #pragma unroll
        for (int m = 0; m < 2; ++m){
          const int R = wr * 32 + m * 16 + lr;
          aF[m] = *reinterpret_cast<const long long*>(&lA[(size_t)R * 128 + ch * 16 + bo]);
        }
        const int Rb = wc * 16 + lr;
        bL = *reinterpret_cast<const long long*>(&lBlo[(size_t)Rb * 128 + ch * 16 + bo]);
        bH = *reinterpret_cast<const long long*>(&lBhi[(size_t)Rb * 128 + ch * 16 + bo]);
        #pragma unroll
        for (int m = 0; m < 2; ++m){
          acc2[m] = __builtin_amdgcn_mfma_f32_16x16x32_fp8_fp8(aF[m], bL, acc2[m], 0, 0, 0);
          acc3[m] = __builtin_amdgcn_mfma_f32_16x16x32_fp8_fp8(aF[m], bH, acc3[m], 0, 0, 0);
        }
      }
      __syncthreads();
    }
  }

  // ----- phase 2: du (K=1024, 4 MEGA-tiles of BK=256 = 2 sub-tiles each; 4 barrier phases) -----
  // LDS: A sub-tiles at base+0/+8192; B sub-tiles at base+16384/+24576. Single-buffered.
  f32x4 acc1[2] = {};
  {
    for (int t = 0; t < 4; ++t){
      const int k0 = t * 256;
      const int r = tid >> 3;
      const int kc = (tid & 7) ^ (r & 7);
      // sub-tile 0 (k0..k0+127) and sub-tile 1 (k0+128..k0+255)
      gload16(Ah + (size_t)r * 1024 + k0 + kc * 16,       base +         (size_t)(w * 64) * 16);
      gload16(Ah + (size_t)r * 1024 + k0 + 128 + kc * 16, base + 8192  + (size_t)(w * 64) * 16);
      gload16(Bl + (size_t)r * 1024 + k0 + kc * 16,       base + 16384 + (size_t)(w * 64) * 16);
      gload16(Bl + (size_t)r * 1024 + k0 + 128 + kc * 16, base + 24576 + (size_t)(w * 64) * 16);
      __syncthreads();
      #pragma unroll
      for (int ks = 0; ks < 2; ++ks){
        unsigned char* lA = base + (size_t)ks * 8192;
        unsigned char* lB = base + 16384 + (size_t)ks * 8192;
        #pragma unroll
        for (int kh = 0; kh < 4; ++kh){
          const int ko = kh * 32 + q * 8;
          const int ch = (ko >> 4) ^ (lr & 7);
          const int bo = ko & 15;
          long long aF[2], bL;
          #pragma unroll
          for (int m = 0; m < 2; ++m){
            const int R = wr * 32 + m * 16 + lr;
            aF[m] = *reinterpret_cast<const long long*>(&lA[(size_t)R * 128 + ch * 16 + bo]);
          }
          const int Rb = wc * 16 + lr;
          bL = *reinterpret_cast<const long long*>(&lB[(size_t)Rb * 128 + ch * 16 + bo]);
          #pragma unroll
          for (int m = 0; m < 2; ++m){
            acc1[m] = __builtin_amdgcn_mfma_f32_16x16x32_fp8_fp8(aF[m], bL, acc1[m], 0, 0, 0);
          }
        }
      }
      __syncthreads();
    }
  }

  // ----- epilogues (hi then lo) -----
  #pragma unroll
  for (int m = 0; m < 2; ++m){
    #pragma unroll
    for (int r = 0; r < 4; ++r){
      const int row = bm * 64 + wr * 32 + m * 16 + q * 4 + r;
      const int c   = bn * 64 + wc * 16 + lr;
      const float un = acc3[m][r] + b3[1024 + c];
      const float u  = b2f(stateb[(size_t)row * 2048 + c]);
      const float vv = b2f(stateb[(size_t)row * 2048 + 1024 + c]);
      const float x  = vv - v0a[row];
      const float ux = un * x;
      const float cl = (ux < 10.0f && -10.0f < ux) ? ux : 0.0f;
      out[(size_t)row * 2049 + 1024 + c] = 0.2f * (u + 0.7f - 0.8f * vv) + cl;
    }
  }
  #pragma unroll
  for (int m = 0; m < 2; ++m){
    #pragma unroll
    for (int r = 0; r < 4; ++r){
      const int row = bm * 64 + wr * 32 + m * 16 + q * 4 + r;
      const int c   = bn * 64 + wc * 16 + lr;
      const float un = acc2[m][r] + b3[c];
      const float u  = b2f(stateb[(size_t)row * 2048 + c]);
      const float vv = b2f(stateb[(size_t)row * 2048 + 1024 + c]);
      const float x  = u - u0a[row];
      const float ux = un * x;
      const float cl = (ux < 10.0f && -10.0f < ux) ? ux : 0.0f;
      out[(size_t)row * 2049 + c] = acc1[m][r] + u - u * u * u * (1.0f / 3.0f) - vv + 1.0f + cl;
    }
  }
}

// ---------------- launch ----------------
extern "C" void kernel_launch(void* const* d_in, const int* in_sizes, int n_in,
                              void* d_out, int out_size, void* d_ws, size_t ws_size,
                              hipStream_t stream){
  (void)in_sizes; (void)n_in; (void)out_size; (void)ws_size;
  const float* state = (const float*)d_in[0];
  const float* tp    = (const float*)d_in[1];
  const float* P     = (const float*)d_in[2];
  const float* W1    = (const float*)d_in[3];
  const float* b1    = (const float*)d_in[4];
  const float* W2    = (const float*)d_in[5];
  const float* b2    = (const float*)d_in[6];
  const float* W3    = (const float*)d_in[7];
  const float* b3    = (const float*)d_in[8];
  const float* icW0  = (const float*)d_in[9];
  const float* icb0  = (const float*)d_in[10];
  const float* icW1  = (const float*)d_in[11];
  const float* icb1  = (const float*)d_in[12];
  const float* icW2  = (const float*)d_in[13];
  const float* icb2  = (const float*)d_in[14];
  const float* icU0  = (const float*)d_in[15];
  const float* icU1  = (const float*)d_in[16];
  float* out = (float*)d_out;
  char* ws = (char*)d_ws;

  bfraw* stateb = (bfraw*)(ws + OFF_STATEB);
  unsigned char* state8 = (unsigned char*)(ws + OFF_STATE8);
  unsigned char* hub8   = (unsigned char*)(ws + OFF_HUB);
  bfraw* pt     = (bfraw*)(ws + OFF_PT);
  bfraw* pteig  = (bfraw*)(ws + OFF_PTEIG);
  unsigned char* lm8  = (unsigned char*)(ws + OFF_LM8);
  unsigned char* w1f8 = (unsigned char*)(ws + OFF_W1F8);
  bfraw* icwb   = (bfraw*)(ws + OFF_ICWB);
  unsigned char* w28  = (unsigned char*)(ws + OFF_W28);
  unsigned char* w3f8 = (unsigned char*)(ws + OFF_W38);
  unsigned char* h18  = (unsigned char*)(ws + OFF_H18);
  unsigned char* h28  = (unsigned char*)(ws + OFF_H28);
  float* z1f    = (float*)(ws + OFF_Z1F);
  float* z2pre  = (float*)(ws + OFF_Z2PRE);
  float* spU0   = (float*)(ws + OFF_SPU0);
  float* spU0T  = (float*)(ws + OFF_SPU0T);
  float* spU1   = (float*)(ws + OFF_SPU1);
  float* z0     = (float*)(ws + OFF_Z0);
  float* su1    = (float*)(ws + OFF_SU1);
  float* sv1    = (float*)(ws + OFF_SV1);
  float* u0a    = (float*)(ws + OFF_U0);
  float* v0a    = (float*)(ws + OFF_V0);
  float* rowdot = (float*)(ws + OFF_RD);
  float* rowss  = (float*)(ws + OFF_RS);

  prep_all<<<dim3(8193), 256, 0, stream>>>(W1, icW0, icW1, W2, W3, P, tp,
      icU0, icU1, icb0, icb1, icb2, state, icW2,
      w1f8, icwb, w28, w3f8, pt, pteig, su1, sv1, spU0, spU0T, spU1, z0,
      stateb, state8, hub8, u0a, v0a, rowdot, rowss);

  // Lm + z + h1 in one dispatch (640 blocks)
  gemm_midh1<<<dim3(640), 512, 0, stream>>>(pteig, pt, lm8, stateb, icwb, icb0, icb1,
      z1f, z2pre, state8, w1f8, b1, h18, u0a, v0a, su1, sv1);
  // h2 = tanh(h1 @ W2^T + b2) -> fp8
  gemm_h2<<<dim3(64, 4), 512, 0, stream>>>(h18, w28, b2, h28);
  // out[:, :2048] (1024 TM=64 gemm blocks) + V column (4096 blocks) in one dispatch
  gemm_outv2<<<dim3(5120), 512, 0, stream>>>(hub8, lm8, h28, w3f8, stateb, b3, u0a, v0a,
      rowdot, rowss, z1f, z2pre, spU0T, spU1, z0, icb2, out);
}

// Round 27
// 88.272 us; speedup vs baseline: 1.0245x; 1.0245x over previous
//
#include <hip/hip_runtime.h>
#include <hip/hip_fp8.h>
#include <cstdint>
#include <cstddef>

using short8 = __attribute__((ext_vector_type(8))) short;
using f32x4  = __attribute__((ext_vector_type(4))) float;
using bfraw  = unsigned short;

// ---------------- helpers ----------------
__device__ __forceinline__ bfraw f2b(float f){
  unsigned int u = __builtin_bit_cast(unsigned int, f);
  u += 0x7FFFu + ((u >> 16) & 1u);            // round-to-nearest-even
  return (bfraw)(u >> 16);
}
__device__ __forceinline__ float b2f(bfraw h){
  unsigned int u = ((unsigned int)h) << 16;
  return __builtin_bit_cast(float, u);
}
__device__ __forceinline__ unsigned char f2f8(float f){   // OCP e4m3fn
  __hip_fp8_e4m3 t(f);
  return (unsigned char)t.__x;
}
__device__ __forceinline__ float srelu(float x){ // smooth_relu, d=0.1
  float r = fmaxf(x, 0.0f);
  if (r < 0.1f){ float r2 = r * r; return (0.2f * r2 * r - r2 * r2) * 500.0f; }
  return x - 0.05f;
}
__device__ __forceinline__ float softplusf(float x){
  return (x > 15.0f) ? x : log1pf(expf(x));
}
__device__ __forceinline__ void gload16(const void* g, void* s){
  __builtin_amdgcn_global_load_lds((const __attribute__((address_space(1))) void*)g,
                                   (__attribute__((address_space(3))) void*)s, 16, 0, 0);
}
// counted vmcnt wait (T4)
template<int N> __device__ __forceinline__ void wait_vm(){
  if constexpr (N == 0)      asm volatile("s_waitcnt vmcnt(0)" ::: "memory");
  else if constexpr (N == 2) asm volatile("s_waitcnt vmcnt(2)" ::: "memory");
  else if constexpr (N == 3) asm volatile("s_waitcnt vmcnt(3)" ::: "memory");
  else                       asm volatile("s_waitcnt vmcnt(4)" ::: "memory");
}
__device__ __forceinline__ void block_barrier(){
  __builtin_amdgcn_s_barrier();
  asm volatile("" ::: "memory");
}

// ---------------- workspace layout (bytes) ----------------
constexpr size_t OFF_STATEB = 0;               // 4096*2048 bf16 = 16MB
constexpr size_t OFF_STATE8 = 16777216;        // 4096*2048 fp8 = 8MB
constexpr size_t OFF_HUB    = 25165824;        // 4096*1024 fp8 = 4MB
constexpr size_t OFF_PT     = 29360128;        // 1024*1024 bf16 = 2MB
constexpr size_t OFF_PTEIG  = 31457280;        // 1024*1024 bf16 = 2MB
constexpr size_t OFF_LM8    = 33554432;        // 1024*1024 fp8 = 1MB
constexpr size_t OFF_W1F8   = 34603008;        // 512*2048 fp8 = 1MB
constexpr size_t OFF_ICWB   = 35651584;        // 128*2048 bf16 = 0.5MB
constexpr size_t OFF_W28    = 36175872;        // 512*512 fp8 = 256KB
constexpr size_t OFF_W38    = 36438016;        // 2048*512 fp8 = 1MB
constexpr size_t OFF_H18    = 37486592;        // 4096*512 fp8 = 2MB
constexpr size_t OFF_H28    = 39583744;        // 4096*512 fp8 = 2MB
constexpr size_t OFF_Z1F    = 41680896;        // 4096*64 f32 = 1MB
constexpr size_t OFF_Z2PRE  = 42729472;        // 4096*64 f32 = 1MB
constexpr size_t OFF_SPU0   = 43778048;        // 64*64 f32
constexpr size_t OFF_SPU1   = 43794432;        // 64 f32
constexpr size_t OFF_Z0     = 43794688;        // 1 f32 (padded)
constexpr size_t OFF_SU1    = 43794944;        // 512 f32
constexpr size_t OFF_SV1    = 43796992;        // 512 f32
constexpr size_t OFF_U0     = 43799040;        // 4096 f32
constexpr size_t OFF_V0     = 43815424;        // 4096 f32
constexpr size_t OFF_RD     = 43831808;        // 4096 f32 (rowdot = icW2 . state_row)
constexpr size_t OFF_RS     = 43848192;        // 4096 f32 (rowss = ||state_row||^2)
constexpr size_t OFF_SPU0T  = 43864576;        // 64*64 f32 (spU0 transposed: [j][n])

// ---------------- merged prep (identical to R25) ----------------
__global__ __launch_bounds__(256) void prep_all(const float* __restrict__ W1,
    const float* __restrict__ icW0, const float* __restrict__ icW1,
    const float* __restrict__ W2, const float* __restrict__ W3,
    const float* __restrict__ P, const float* __restrict__ tptr,
    const float* __restrict__ icU0, const float* __restrict__ icU1,
    const float* __restrict__ icb0, const float* __restrict__ icb1, const float* __restrict__ icb2,
    const float* __restrict__ state, const float* __restrict__ icW2,
    unsigned char* __restrict__ w1f8, bfraw* __restrict__ icwb,
    unsigned char* __restrict__ w28, unsigned char* __restrict__ w3f8,
    bfraw* __restrict__ PT, bfraw* __restrict__ PTeig,
    float* __restrict__ su1, float* __restrict__ sv1,
    float* __restrict__ spU0, float* __restrict__ spU0T,
    float* __restrict__ spU1, float* __restrict__ z0out,
    bfraw* __restrict__ stateb, unsigned char* __restrict__ state8, unsigned char* __restrict__ hub8,
    float* __restrict__ u0a, float* __restrict__ v0a,
    float* __restrict__ rowdot, float* __restrict__ rowss){
  __shared__ float smem[4288];
  const int b = blockIdx.x;
  const int t = threadIdx.x;
  if (b < 2560){
    const int i4 = (b * 256 + t) * 4;
    if (i4 >= 1048576 && i4 < 1310720){
      const float* src = (i4 < 1179648) ? icW0 : icW1;
      const int off = (i4 < 1179648) ? (i4 - 1048576) : (i4 - 1179648);
      const int dsto = i4 - 1048576;
      float4 v = *reinterpret_cast<const float4*>(src + off);
      ushort4 o;
      o.x = f2b(v.x); o.y = f2b(v.y); o.z = f2b(v.z); o.w = f2b(v.w);
      *reinterpret_cast<ushort4*>(icwb + dsto) = o;
    } else {
      const float* src; unsigned char* dst; int off;
      if (i4 < 1048576)      { src = W1; dst = w1f8; off = i4; }
      else if (i4 < 1572864) { src = W2; dst = w28;  off = i4 - 1310720; }
      else                   { src = W3; dst = w3f8; off = i4 - 1572864; }
      float4 v = *reinterpret_cast<const float4*>(src + off);
      uchar4 o;
      o.x = f2f8(v.x); o.y = f2f8(v.y); o.z = f2f8(v.z); o.w = f2f8(v.w);
      *reinterpret_cast<uchar4*>(dst + off) = o;
    }
  } else if (b < 3584){
    float (*tile)[33] = (float(*)[33])smem;
    const int idx = b - 2560;
    const int bi = idx >> 5, bj = idx & 31;
    const int tx = t & 31, ty = t >> 5;
    #pragma unroll
    for (int r = 0; r < 4; ++r){
      const int k = bj * 32 + ty + r * 8;
      const int i = bi * 32 + tx;
      tile[ty + r * 8][tx] = P[(size_t)k * 1024 + i];
    }
    __syncthreads();
    const float s = 2.0f * sinf(tptr[0]);
    #pragma unroll
    for (int r = 0; r < 4; ++r){
      const int i = bi * 32 + ty + r * 8;
      const int k = bj * 32 + tx;
      const float p = tile[tx][ty + r * 8];
      const float e = (k == 0) ? 0.0f : ((k <= 511) ? (1.0f + s) : (1.0f - s));
      PT[(size_t)i * 1024 + k] = f2b(p);
      PTeig[(size_t)i * 1024 + k] = f2b(e * p);
    }
  } else if (b < 4096){
    const int n = b - 3584;
    float a = 0.0f, bb = 0.0f;
    for (int j = t; j < 1024; j += 256) a += W1[(size_t)n * 2048 + j];
    for (int j = t; j < 1024; j += 256) bb += W1[(size_t)n * 2048 + 1024 + j];
    #pragma unroll
    for (int o = 32; o > 0; o >>= 1){ a += __shfl_down(a, o, 64); bb += __shfl_down(bb, o, 64); }
    if ((t & 63) == 0){ smem[t >> 6] = a; smem[4 + (t >> 6)] = bb; }
    __syncthreads();
    if (t == 0){
      su1[n] = smem[0] + smem[1] + smem[2] + smem[3];
      sv1[n] = smem[4] + smem[5] + smem[6] + smem[7];
    }
  } else if (b == 4096){
    float* sp  = smem;
    float* sp1 = smem + 4096;
    float* a0  = smem + 4160;
    float* a1  = smem + 4224;
    #pragma unroll
    for (int i = 0; i < 16; ++i){
      const int idx = i * 256 + t;
      const float v = softplusf(icU0[idx]);
      sp[idx] = v;
      spU0[idx] = v;
      spU0T[(idx & 63) * 64 + (idx >> 6)] = v;   // transposed copy [j][n]
    }
    if (t < 64){
      const float v1 = softplusf(icU1[t]);
      sp1[t] = v1;
      spU1[t] = v1;
      a0[t] = srelu(icb0[t]);
    }
    __syncthreads();
    {
      const int n = t >> 2, q = t & 3;
      float sAcc = 0.0f;
      #pragma unroll
      for (int j = 0; j < 16; ++j) sAcc += sp[n * 64 + q * 16 + j] * a0[q * 16 + j];
      sAcc += __shfl_down(sAcc, 2, 64);
      sAcc += __shfl_down(sAcc, 1, 64);
      if (q == 0) a1[n] = srelu(sAcc + icb1[n]);
    }
    __syncthreads();
    if (t < 64){
      float v = sp1[t] * a1[t];
      #pragma unroll
      for (int o = 32; o > 0; o >>= 1) v += __shfl_down(v, o, 64);
      if (t == 0) z0out[0] = srelu(v + icb2[0]);
    }
  } else {
    const int row = b - 4097;
    const float* srow = state + (size_t)row * 2048;
    float4 u4 = *reinterpret_cast<const float4*>(srow + t * 4);
    float4 v4 = *reinterpret_cast<const float4*>(srow + 1024 + t * 4);
    float4 wu = *reinterpret_cast<const float4*>(icW2 + t * 4);
    float4 wv = *reinterpret_cast<const float4*>(icW2 + 1024 + t * 4);
    float us[4] = {u4.x, u4.y, u4.z, u4.w};
    float vs[4] = {v4.x, v4.y, v4.z, v4.w};
    float wus[4] = {wu.x, wu.y, wu.z, wu.w};
    float wvs[4] = {wv.x, wv.y, wv.z, wv.w};
    uchar4 h8, s8u, s8v;
    unsigned char* hp = reinterpret_cast<unsigned char*>(&h8);
    unsigned char* su = reinterpret_cast<unsigned char*>(&s8u);
    unsigned char* sv = reinterpret_cast<unsigned char*>(&s8v);
    float d = 0.0f, ss = 0.0f;
    #pragma unroll
    for (int i = 0; i < 4; ++i){
      const int j = t * 4 + i;
      const float u = us[i], v = vs[i];
      stateb[(size_t)row * 2048 + j] = f2b(u);
      stateb[(size_t)row * 2048 + 1024 + j] = f2b(v);
      su[i] = f2f8(u);
      sv[i] = f2f8(v);
      hp[i] = f2f8(1.0f / (1.0f + expf(-10.0f * u)));
      d  = fmaf(wus[i], u, fmaf(wvs[i], v, d));
      ss = fmaf(u, u, fmaf(v, v, ss));
    }
    *reinterpret_cast<uchar4*>(state8 + (size_t)row * 2048 + t * 4) = s8u;
    *reinterpret_cast<uchar4*>(state8 + (size_t)row * 2048 + 1024 + t * 4) = s8v;
    *reinterpret_cast<uchar4*>(hub8 + (size_t)row * 1024 + t * 4) = h8;
    #pragma unroll
    for (int o = 32; o > 0; o >>= 1){ d += __shfl_down(d, o, 64); ss += __shfl_down(ss, o, 64); }
    if ((t & 63) == 0){ smem[t >> 6] = d; smem[4 + (t >> 6)] = ss; }
    __syncthreads();
    if (t == 0){
      rowdot[row] = smem[0] + smem[1] + smem[2] + smem[3];
      rowss[row]  = smem[4] + smem[5] + smem[6] + smem[7];
      u0a[row] = srow[0]; v0a[row] = srow[1024];
    }
  }
}

// ---------------- merged mid (Lm bf16 + z bf16) + h1 (fp8) in ONE dispatch, 640 blocks ----------------
__global__ __launch_bounds__(512)
void gemm_midh1(const bfraw* __restrict__ pteig, const bfraw* __restrict__ pt,
                unsigned char* __restrict__ lm8,
                const bfraw* __restrict__ stateb, const bfraw* __restrict__ icwb,
                const float* __restrict__ icb0, const float* __restrict__ icb1,
                float* __restrict__ z1f, float* __restrict__ z2pre,
                const unsigned char* __restrict__ state8, const unsigned char* __restrict__ w1f8,
                const float* __restrict__ b1, unsigned char* __restrict__ h18,
                const float* __restrict__ u0a, const float* __restrict__ v0a,
                const float* __restrict__ su1, const float* __restrict__ sv1)
{
  __shared__ char ldsRaw[73728];     // 72KB union
  const int blk = blockIdx.x;
  const int tid = threadIdx.x;
  const int w  = tid >> 6;
  const int l  = tid & 63;
  const int lr = l & 15;
  const int q  = l >> 4;

  if (blk < 384){
    bfraw* lA = (bfraw*)ldsRaw;
    bfraw* lB = (bfraw*)(ldsRaw + 24576);
    const bool isLm = (blk < 256);
    const bfraw* A; const bfraw* B; int K, bm, bn;
    if (isLm){ A = pteig; B = pt; K = 1024; bm = blk >> 4; bn = blk & 15; }
    else     { const int i = blk - 256; A = stateb; B = icwb; K = 2048; bm = i >> 1; bn = i & 1; }
    const int wr = w >> 2;
    const int wc = w & 3;
    f32x4 acc[2] = {};
    const int nt = K >> 6;
    auto stage = [&](int buf, int k0){
      const int r = tid >> 3;
      const int kc = (tid & 7) ^ (r & 7);
      gload16(A + (size_t)(bm * 64 + r) * K + k0 + kc * 8, &lA[(size_t)buf * 4096 + (size_t)(w * 64) * 8]);
      gload16(B + (size_t)(bn * 64 + r) * K + k0 + kc * 8, &lB[(size_t)buf * 4096 + (size_t)(w * 64) * 8]);
    };
    stage(0, 0);
    stage(1, 64);
    for (int t = 0; t < nt; ++t){
      const int cur = t % 3;
      if (t == nt - 1) wait_vm<0>(); else wait_vm<2>();
      block_barrier();
      short8 aF[2][2], bF[2];
      #pragma unroll
      for (int kh = 0; kh < 2; ++kh){
        const int kch = (kh * 4 + q) ^ (lr & 7);
        #pragma unroll
        for (int m = 0; m < 2; ++m){
          const int R = wr * 32 + m * 16 + lr;
          aF[kh][m] = *reinterpret_cast<const short8*>(&lA[(size_t)cur * 4096 + (size_t)R * 64 + kch * 8]);
        }
        const int R = wc * 16 + lr;
        bF[kh] = *reinterpret_cast<const short8*>(&lB[(size_t)cur * 4096 + (size_t)R * 64 + kch * 8]);
      }
      if (t + 2 < nt) stage((t + 2) % 3, (t + 2) * 64);
      #pragma unroll
      for (int kh = 0; kh < 2; ++kh)
        #pragma unroll
        for (int m = 0; m < 2; ++m)
          acc[m] = __builtin_amdgcn_mfma_f32_16x16x32_bf16(aF[kh][m], bF[kh], acc[m], 0, 0, 0);
    }
    #pragma unroll
    for (int m = 0; m < 2; ++m){
      #pragma unroll
      for (int r = 0; r < 4; ++r){
        const int row = bm * 64 + (w >> 2) * 32 + m * 16 + q * 4 + r;
        const int c64 = (w & 3) * 16 + lr;
        const float v = acc[m][r];
        if (isLm){
          lm8[(size_t)row * 1024 + bn * 64 + c64] = f2f8(v);
        } else if (bn == 0){
          z1f[(size_t)row * 64 + c64] = srelu(v + icb0[c64]);
        } else {
          z2pre[(size_t)row * 64 + c64] = v + icb1[c64];
        }
      }
    }
  } else {
    unsigned char* lA = (unsigned char*)ldsRaw;
    unsigned char* lB = (unsigned char*)(ldsRaw + 24576);
    const int i = blk - 384;
    const int bm = i >> 2;
    const int bn = i & 3;
    const int wr = w >> 2;
    const int wc = w & 3;
    constexpr int K = 2048;
    f32x4 acc[2][2] = {};
    const int nt = K >> 7;
    auto stage = [&](int buf, int k0){
      {
        const int c = tid;
        const int r = c >> 3;
        const int kc = (c & 7) ^ (r & 7);
        gload16(state8 + (size_t)(bm * 64 + r) * K + k0 + kc * 16, &lA[(size_t)buf * 8192 + (size_t)(w * 64) * 16]);
      }
      #pragma unroll
      for (int j = 0; j < 2; ++j){
        const int c = j * 512 + tid;
        const int r = c >> 3;
        const int kc = (c & 7) ^ (r & 7);
        gload16(w1f8 + (size_t)(bn * 128 + r) * K + k0 + kc * 16, &lB[(size_t)buf * 16384 + (size_t)(j * 512 + w * 64) * 16]);
      }
    };
    stage(0, 0);
    stage(1, 128);
    for (int t = 0; t < nt; ++t){
      const int cur = t % 3;
      if (t == nt - 1) wait_vm<0>(); else wait_vm<3>();
      block_barrier();
      long long aF[4][2], bF[4][2];
      #pragma unroll
      for (int kh = 0; kh < 4; ++kh){
        const int ko = kh * 32 + q * 8;
        const int ch = (ko >> 4) ^ (lr & 7);
        const int bo = ko & 15;
        #pragma unroll
        for (int m = 0; m < 2; ++m){
          const int R = wr * 32 + m * 16 + lr;
          aF[kh][m] = *reinterpret_cast<const long long*>(&lA[(size_t)cur * 8192 + (size_t)R * 128 + ch * 16 + bo]);
        }
        #pragma unroll
        for (int n = 0; n < 2; ++n){
          const int R = wc * 32 + n * 16 + lr;
          bF[kh][n] = *reinterpret_cast<const long long*>(&lB[(size_t)cur * 16384 + (size_t)R * 128 + ch * 16 + bo]);
        }
      }
      if (t + 2 < nt) stage((t + 2) % 3, (t + 2) * 128);
      #pragma unroll
      for (int kh = 0; kh < 4; ++kh)
        #pragma unroll
        for (int m = 0; m < 2; ++m)
          #pragma unroll
          for (int n = 0; n < 2; ++n)
            acc[m][n] = __builtin_amdgcn_mfma_f32_16x16x32_fp8_fp8(aF[kh][m], bF[kh][n], acc[m][n], 0, 0, 0);
    }
    #pragma unroll
    for (int m = 0; m < 2; ++m){
      #pragma unroll
      for (int n = 0; n < 2; ++n){
        #pragma unroll
        for (int r = 0; r < 4; ++r){
          const int row = bm * 64 + wr * 32 + m * 16 + q * 4 + r;
          const int col = bn * 128 + wc * 32 + n * 16 + lr;
          const float h = acc[m][n][r] - u0a[row] * su1[col] - v0a[row] * sv1[col] + b1[col];
          h18[(size_t)row * 512 + col] = f2f8(tanhf(h));
        }
      }
    }
  }
}

// ---------------- h2 = tanh(h1 @ W2^T + b2) -> fp8 ----------------
__global__ __launch_bounds__(512)
void gemm_h2(const unsigned char* __restrict__ A, const unsigned char* __restrict__ B,
             const float* __restrict__ bias, unsigned char* __restrict__ outf8)
{
  constexpr int N = 512, K = 512;
  __shared__ unsigned char lA[3][64 * 128];
  __shared__ unsigned char lB[3][128 * 128];
  const int tid = threadIdx.x;
  const int w  = tid >> 6;
  const int l  = tid & 63;
  const int wr = w >> 2;
  const int wc = w & 3;
  const int bm = blockIdx.x;
  const int bn = blockIdx.y;
  const int lr = l & 15;
  const int q  = l >> 4;
  f32x4 acc[2][2] = {};
  const int nt = K >> 7;
  auto stage = [&](int buf, int k0){
    {
      const int c = tid;
      const int r = c >> 3;
      const int kc = (c & 7) ^ (r & 7);
      gload16(A + (size_t)(bm * 64 + r) * K + k0 + kc * 16, &lA[buf][(size_t)(w * 64) * 16]);
    }
    #pragma unroll
    for (int j = 0; j < 2; ++j){
      const int c = j * 512 + tid;
      const int r = c >> 3;
      const int kc = (c & 7) ^ (r & 7);
      gload16(B + (size_t)(bn * 128 + r) * K + k0 + kc * 16, &lB[buf][(size_t)(j * 512 + w * 64) * 16]);
    }
  };
  stage(0, 0);
  stage(1, 128);
  for (int t = 0; t < nt; ++t){
    const int cur = t % 3;
    if (t == nt - 1) wait_vm<0>(); else wait_vm<3>();
    block_barrier();
    long long aF[4][2], bF[4][2];
    #pragma unroll
    for (int kh = 0; kh < 4; ++kh){
      const int ko = kh * 32 + q * 8;
      const int ch = (ko >> 4) ^ (lr & 7);
      const int bo = ko & 15;
      #pragma unroll
      for (int m = 0; m < 2; ++m){
        const int R = wr * 32 + m * 16 + lr;
        aF[kh][m] = *reinterpret_cast<const long long*>(&lA[cur][(size_t)R * 128 + ch * 16 + bo]);
      }
      #pragma unroll
      for (int n = 0; n < 2; ++n){
        const int R = wc * 32 + n * 16 + lr;
        bF[kh][n] = *reinterpret_cast<const long long*>(&lB[cur][(size_t)R * 128 + ch * 16 + bo]);
      }
    }
    if (t + 2 < nt) stage((t + 2) % 3, (t + 2) * 128);
    #pragma unroll
    for (int kh = 0; kh < 4; ++kh)
      #pragma unroll
      for (int m = 0; m < 2; ++m)
        #pragma unroll
        for (int n = 0; n < 2; ++n)
          acc[m][n] = __builtin_amdgcn_mfma_f32_16x16x32_fp8_fp8(aF[kh][m], bF[kh][n], acc[m][n], 0, 0, 0);
  }
  #pragma unroll
  for (int m = 0; m < 2; ++m){
    #pragma unroll
    for (int n = 0; n < 2; ++n){
      #pragma unroll
      for (int r = 0; r < 4; ++r){
        const int row = bm * 64 + wr * 32 + m * 16 + q * 4 + r;
        const int col = bn * 128 + wc * 32 + n * 16 + lr;
        outf8[(size_t)row * N + col] = f2f8(tanhf(acc[m][n][r] + bias[col]));
      }
    }
  }
}

// ---------------- merged out + v2 (R25-verified: TM=64 single-buffer + XCD remap) ----------------
__global__ __launch_bounds__(512, 4)
void gemm_outv2(const unsigned char* __restrict__ hub8, const unsigned char* __restrict__ lm8,
                const unsigned char* __restrict__ h2b8, const unsigned char* __restrict__ w3f8,
                const bfraw* __restrict__ stateb, const float* __restrict__ b3,
                const float* __restrict__ u0a, const float* __restrict__ v0a,
                const float* __restrict__ rowdot, const float* __restrict__ rowss,
                const float* __restrict__ z1f, const float* __restrict__ z2pre,
                const float* __restrict__ spU0T, const float* __restrict__ spU1,
                const float* __restrict__ z0p, const float* __restrict__ icb2,
                float* __restrict__ out)
{
  __shared__ char ldsRaw[24576 + 512];
  const int blk = blockIdx.x;
  const int tid = threadIdx.x;

  if (blk >= 1024){
    // ----- v2 role: tiny — z2 matvec (coalesced spU0T) + combine -----
    float* z1s = (float*)ldsRaw;
    const int row = blk - 1024;
    if (tid < 64) z1s[tid] = z1f[(size_t)row * 64 + tid];
    __syncthreads();
    if (tid < 64){
      float acc2 = z2pre[(size_t)row * 64 + tid];
      #pragma unroll 8
      for (int j = 0; j < 64; ++j) acc2 += spU0T[j * 64 + tid] * z1s[j];
      float dd = spU1[tid] * srelu(acc2);
      #pragma unroll
      for (int o = 32; o > 0; o >>= 1) dd += __shfl_down(dd, o, 64);
      if (tid == 0){
        const float D = dd + rowdot[row];
        const float z3 = srelu(D + icb2[0]);
        out[(size_t)row * 2049 + 2048] = srelu(z3 - z0p[0]) + 0.001f * rowss[row];
      }
    }
    return;
  }

  // ----- gemm role: TM=64, single-buffer (R23-verified) + XCD-aware block remap -----
  unsigned char* lA   = (unsigned char*)ldsRaw;            // 8KB (64x128)
  unsigned char* lBlo = (unsigned char*)(ldsRaw + 8192);   // 8KB
  unsigned char* lBhi = (unsigned char*)(ldsRaw + 16384);  // 8KB
  const int w  = tid >> 6;
  const int l  = tid & 63;
  const int wr = w >> 2;          // 0..1 (row halves of 64)
  const int wc = w & 3;           // 0..3
  const int xcd = blk & 7;
  const int ii  = blk >> 3;       // 0..127
  const int bm  = xcd * 8 + (ii >> 4);   // 0..63
  const int bn  = ii & 15;               // 0..15
  const int lr = l & 15;
  const int q  = l >> 4;

  const unsigned char* Au  = h2b8 + (size_t)(bm * 64) * 512;
  const unsigned char* Bwl = w3f8 + (size_t)(bn * 64) * 512;
  const unsigned char* Bwh = w3f8 + (size_t)(1024 + bn * 64) * 512;
  const unsigned char* Ah  = hub8 + (size_t)(bm * 64) * 1024;
  const unsigned char* Bl  = lm8  + (size_t)(bn * 64) * 1024;

  f32x4 acc2[2] = {};   // un lo
  f32x4 acc3[2] = {};   // un hi

  for (int t = 0; t < 4; ++t){
    const int k0 = t * 128;
    const int r = tid >> 3;
    const int kc = (tid & 7) ^ (r & 7);
    gload16(Au  + (size_t)r * 512 + k0 + kc * 16, &lA  [(size_t)(w * 64) * 16]);
    gload16(Bwl + (size_t)r * 512 + k0 + kc * 16, &lBlo[(size_t)(w * 64) * 16]);
    gload16(Bwh + (size_t)r * 512 + k0 + kc * 16, &lBhi[(size_t)(w * 64) * 16]);
    __syncthreads();
    #pragma unroll
    for (int kh = 0; kh < 4; ++kh){
      const int ko = kh * 32 + q * 8;
      const int ch = (ko >> 4) ^ (lr & 7);
      const int bo = ko & 15;
      long long aF[2], bL, bH;
      #pragma unroll
      for (int m = 0; m < 2; ++m){
        const int R = wr * 32 + m * 16 + lr;
        aF[m] = *reinterpret_cast<const long long*>(&lA[(size_t)R * 128 + ch * 16 + bo]);
      }
      const int Rb = wc * 16 + lr;
      bL = *reinterpret_cast<const long long*>(&lBlo[(size_t)Rb * 128 + ch * 16 + bo]);
      bH = *reinterpret_cast<const long long*>(&lBhi[(size_t)Rb * 128 + ch * 16 + bo]);
      #pragma unroll
      for (int m = 0; m < 2; ++m){
        acc2[m] = __builtin_amdgcn_mfma_f32_16x16x32_fp8_fp8(aF[m], bL, acc2[m], 0, 0, 0);
        acc3[m] = __builtin_amdgcn_mfma_f32_16x16x32_fp8_fp8(aF[m], bH, acc3[m], 0, 0, 0);
      }
    }
    __syncthreads();
  }

  #pragma unroll
  for (int m = 0; m < 2; ++m){
    #pragma unroll
    for (int r = 0; r < 4; ++r){
      const int row = bm * 64 + wr * 32 + m * 16 + q * 4 + r;
      const int c   = bn * 64 + wc * 16 + lr;
      const float un = acc3[m][r] + b3[1024 + c];
      const float u  = b2f(stateb[(size_t)row * 2048 + c]);
      const float vv = b2f(stateb[(size_t)row * 2048 + 1024 + c]);
      const float x  = vv - v0a[row];
      const float ux = un * x;
      const float cl = (ux < 10.0f && -10.0f < ux) ? ux : 0.0f;
      out[(size_t)row * 2049 + 1024 + c] = 0.2f * (u + 0.7f - 0.8f * vv) + cl;
    }
  }

  f32x4 acc1[2] = {};
  for (int t = 0; t < 8; ++t){
    const int k0 = t * 128;
    const int r = tid >> 3;
    const int kc = (tid & 7) ^ (r & 7);
    gload16(Ah + (size_t)r * 1024 + k0 + kc * 16, &lA  [(size_t)(w * 64) * 16]);
    gload16(Bl + (size_t)r * 1024 + k0 + kc * 16, &lBlo[(size_t)(w * 64) * 16]);
    __syncthreads();
    #pragma unroll
    for (int kh = 0; kh < 4; ++kh){
      const int ko = kh * 32 + q * 8;
      const int ch = (ko >> 4) ^ (lr & 7);
      const int bo = ko & 15;
      long long aF[2], bL;
      #pragma unroll
      for (int m = 0; m < 2; ++m){
        const int R = wr * 32 + m * 16 + lr;
        aF[m] = *reinterpret_cast<const long long*>(&lA[(size_t)R * 128 + ch * 16 + bo]);
      }
      const int Rb = wc * 16 + lr;
      bL = *reinterpret_cast<const long long*>(&lBlo[(size_t)Rb * 128 + ch * 16 + bo]);
      #pragma unroll
      for (int m = 0; m < 2; ++m){
        acc1[m] = __builtin_amdgcn_mfma_f32_16x16x32_fp8_fp8(aF[m], bL, acc1[m], 0, 0, 0);
      }
    }
    __syncthreads();
  }

  #pragma unroll
  for (int m = 0; m < 2; ++m){
    #pragma unroll
    for (int r = 0; r < 4; ++r){
      const int row = bm * 64 + wr * 32 + m * 16 + q * 4 + r;
      const int c   = bn * 64 + wc * 16 + lr;
      const float un = acc2[m][r] + b3[c];
      const float u  = b2f(stateb[(size_t)row * 2048 + c]);
      const float vv = b2f(stateb[(size_t)row * 2048 + 1024 + c]);
      const float x  = u - u0a[row];
      const float ux = un * x;
      const float cl = (ux < 10.0f && -10.0f < ux) ? ux : 0.0f;
      out[(size_t)row * 2049 + c] = acc1[m][r] + u - u * u * u * (1.0f / 3.0f) - vv + 1.0f + cl;
    }
  }
}

// ---------------- launch ----------------
extern "C" void kernel_launch(void* const* d_in, const int* in_sizes, int n_in,
                              void* d_out, int out_size, void* d_ws, size_t ws_size,
                              hipStream_t stream){
  (void)in_sizes; (void)n_in; (void)out_size; (void)ws_size;
  const float* state = (const float*)d_in[0];
  const float* tp    = (const float*)d_in[1];
  const float* P     = (const float*)d_in[2];
  const float* W1    = (const float*)d_in[3];
  const float* b1    = (const float*)d_in[4];
  const float* W2    = (const float*)d_in[5];
  const float* b2    = (const float*)d_in[6];
  const float* W3    = (const float*)d_in[7];
  const float* b3    = (const float*)d_in[8];
  const float* icW0  = (const float*)d_in[9];
  const float* icb0  = (const float*)d_in[10];
  const float* icW1  = (const float*)d_in[11];
  const float* icb1  = (const float*)d_in[12];
  const float* icW2  = (const float*)d_in[13];
  const float* icb2  = (const float*)d_in[14];
  const float* icU0  = (const float*)d_in[15];
  const float* icU1  = (const float*)d_in[16];
  float* out = (float*)d_out;
  char* ws = (char*)d_ws;

  bfraw* stateb = (bfraw*)(ws + OFF_STATEB);
  unsigned char* state8 = (unsigned char*)(ws + OFF_STATE8);
  unsigned char* hub8   = (unsigned char*)(ws + OFF_HUB);
  bfraw* pt     = (bfraw*)(ws + OFF_PT);
  bfraw* pteig  = (bfraw*)(ws + OFF_PTEIG);
  unsigned char* lm8  = (unsigned char*)(ws + OFF_LM8);
  unsigned char* w1f8 = (unsigned char*)(ws + OFF_W1F8);
  bfraw* icwb   = (bfraw*)(ws + OFF_ICWB);
  unsigned char* w28  = (unsigned char*)(ws + OFF_W28);
  unsigned char* w3f8 = (unsigned char*)(ws + OFF_W38);
  unsigned char* h18  = (unsigned char*)(ws + OFF_H18);
  unsigned char* h28  = (unsigned char*)(ws + OFF_H28);
  float* z1f    = (float*)(ws + OFF_Z1F);
  float* z2pre  = (float*)(ws + OFF_Z2PRE);
  float* spU0   = (float*)(ws + OFF_SPU0);
  float* spU0T  = (float*)(ws + OFF_SPU0T);
  float* spU1   = (float*)(ws + OFF_SPU1);
  float* z0     = (float*)(ws + OFF_Z0);
  float* su1    = (float*)(ws + OFF_SU1);
  float* sv1    = (float*)(ws + OFF_SV1);
  float* u0a    = (float*)(ws + OFF_U0);
  float* v0a    = (float*)(ws + OFF_V0);
  float* rowdot = (float*)(ws + OFF_RD);
  float* rowss  = (float*)(ws + OFF_RS);

  prep_all<<<dim3(8193), 256, 0, stream>>>(W1, icW0, icW1, W2, W3, P, tp,
      icU0, icU1, icb0, icb1, icb2, state, icW2,
      w1f8, icwb, w28, w3f8, pt, pteig, su1, sv1, spU0, spU0T, spU1, z0,
      stateb, state8, hub8, u0a, v0a, rowdot, rowss);

  // Lm + z + h1 in one dispatch (640 blocks)
  gemm_midh1<<<dim3(640), 512, 0, stream>>>(pteig, pt, lm8, stateb, icwb, icb0, icb1,
      z1f, z2pre, state8, w1f8, b1, h18, u0a, v0a, su1, sv1);
  // h2 = tanh(h1 @ W2^T + b2) -> fp8
  gemm_h2<<<dim3(64, 4), 512, 0, stream>>>(h18, w28, b2, h28);
  // out[:, :2048] (1024 TM=64 gemm blocks) + V column (4096 blocks) in one dispatch
  gemm_outv2<<<dim3(5120), 512, 0, stream>>>(hub8, lm8, h28, w3f8, stateb, b3, u0a, v0a,
      rowdot, rowss, z1f, z2pre, spU0T, spU1, z0, icb2, out);
}

// Round 28
// 86.359 us; speedup vs baseline: 1.0472x; 1.0222x over previous
//
#include <hip/hip_runtime.h>
#include <hip/hip_fp8.h>
#include <cstdint>
#include <cstddef>

using short8 = __attribute__((ext_vector_type(8))) short;
using f32x4  = __attribute__((ext_vector_type(4))) float;
using bfraw  = unsigned short;

// ---------------- helpers ----------------
__device__ __forceinline__ bfraw f2b(float f){
  unsigned int u = __builtin_bit_cast(unsigned int, f);
  u += 0x7FFFu + ((u >> 16) & 1u);            // round-to-nearest-even
  return (bfraw)(u >> 16);
}
__device__ __forceinline__ float b2f(bfraw h){
  unsigned int u = ((unsigned int)h) << 16;
  return __builtin_bit_cast(float, u);
}
__device__ __forceinline__ unsigned char f2f8(float f){   // OCP e4m3fn
  __hip_fp8_e4m3 t(f);
  return (unsigned char)t.__x;
}
__device__ __forceinline__ float srelu(float x){ // smooth_relu, d=0.1
  float r = fmaxf(x, 0.0f);
  if (r < 0.1f){ float r2 = r * r; return (0.2f * r2 * r - r2 * r2) * 500.0f; }
  return x - 0.05f;
}
__device__ __forceinline__ float softplusf(float x){
  return (x > 15.0f) ? x : log1pf(expf(x));
}
__device__ __forceinline__ void gload16(const void* g, void* s){
  __builtin_amdgcn_global_load_lds((const __attribute__((address_space(1))) void*)g,
                                   (__attribute__((address_space(3))) void*)s, 16, 0, 0);
}
// counted vmcnt wait (T4)
template<int N> __device__ __forceinline__ void wait_vm(){
  if constexpr (N == 0)      asm volatile("s_waitcnt vmcnt(0)" ::: "memory");
  else if constexpr (N == 2) asm volatile("s_waitcnt vmcnt(2)" ::: "memory");
  else if constexpr (N == 3) asm volatile("s_waitcnt vmcnt(3)" ::: "memory");
  else                       asm volatile("s_waitcnt vmcnt(4)" ::: "memory");
}
__device__ __forceinline__ void block_barrier(){
  __builtin_amdgcn_s_barrier();
  asm volatile("" ::: "memory");
}

// ---------------- workspace layout (bytes) ----------------
constexpr size_t OFF_STATEB = 0;               // 4096*2048 bf16 = 16MB
constexpr size_t OFF_STATE8 = 16777216;        // 4096*2048 fp8 = 8MB
constexpr size_t OFF_HUB    = 25165824;        // 4096*1024 fp8 = 4MB
constexpr size_t OFF_PT     = 29360128;        // 1024*1024 bf16 = 2MB
constexpr size_t OFF_PTEIG  = 31457280;        // 1024*1024 bf16 = 2MB
constexpr size_t OFF_LM8    = 33554432;        // 1024*1024 fp8 = 1MB
constexpr size_t OFF_W1F8   = 34603008;        // 512*2048 fp8 = 1MB
constexpr size_t OFF_ICWB   = 35651584;        // 128*2048 bf16 = 0.5MB
constexpr size_t OFF_W28    = 36175872;        // 512*512 fp8 = 256KB
constexpr size_t OFF_W38    = 36438016;        // 2048*512 fp8 = 1MB
constexpr size_t OFF_H18    = 37486592;        // 4096*512 fp8 = 2MB
constexpr size_t OFF_H28    = 39583744;        // 4096*512 fp8 = 2MB
constexpr size_t OFF_Z1F    = 41680896;        // 4096*64 f32 = 1MB
constexpr size_t OFF_Z2PRE  = 42729472;        // 4096*64 f32 = 1MB
constexpr size_t OFF_SPU0   = 43778048;        // 64*64 f32
constexpr size_t OFF_SPU1   = 43794432;        // 64 f32
constexpr size_t OFF_Z0     = 43794688;        // 1 f32 (padded)
constexpr size_t OFF_SU1    = 43794944;        // 512 f32
constexpr size_t OFF_SV1    = 43796992;        // 512 f32
constexpr size_t OFF_U0     = 43799040;        // 4096 f32
constexpr size_t OFF_V0     = 43815424;        // 4096 f32
constexpr size_t OFF_RD     = 43831808;        // 4096 f32 (rowdot = icW2 . state_row)
constexpr size_t OFF_RS     = 43848192;        // 4096 f32 (rowss = ||state_row||^2)
constexpr size_t OFF_SPU0T  = 43864576;        // 64*64 f32 (spU0 transposed: [j][n])

// ---------------- merged prep (identical to R27) ----------------
__global__ __launch_bounds__(256) void prep_all(const float* __restrict__ W1,
    const float* __restrict__ icW0, const float* __restrict__ icW1,
    const float* __restrict__ W2, const float* __restrict__ W3,
    const float* __restrict__ P, const float* __restrict__ tptr,
    const float* __restrict__ icU0, const float* __restrict__ icU1,
    const float* __restrict__ icb0, const float* __restrict__ icb1, const float* __restrict__ icb2,
    const float* __restrict__ state, const float* __restrict__ icW2,
    unsigned char* __restrict__ w1f8, bfraw* __restrict__ icwb,
    unsigned char* __restrict__ w28, unsigned char* __restrict__ w3f8,
    bfraw* __restrict__ PT, bfraw* __restrict__ PTeig,
    float* __restrict__ su1, float* __restrict__ sv1,
    float* __restrict__ spU0, float* __restrict__ spU0T,
    float* __restrict__ spU1, float* __restrict__ z0out,
    bfraw* __restrict__ stateb, unsigned char* __restrict__ state8, unsigned char* __restrict__ hub8,
    float* __restrict__ u0a, float* __restrict__ v0a,
    float* __restrict__ rowdot, float* __restrict__ rowss){
  __shared__ float smem[4288];
  const int b = blockIdx.x;
  const int t = threadIdx.x;
  if (b < 2560){
    const int i4 = (b * 256 + t) * 4;
    if (i4 >= 1048576 && i4 < 1310720){
      const float* src = (i4 < 1179648) ? icW0 : icW1;
      const int off = (i4 < 1179648) ? (i4 - 1048576) : (i4 - 1179648);
      const int dsto = i4 - 1048576;
      float4 v = *reinterpret_cast<const float4*>(src + off);
      ushort4 o;
      o.x = f2b(v.x); o.y = f2b(v.y); o.z = f2b(v.z); o.w = f2b(v.w);
      *reinterpret_cast<ushort4*>(icwb + dsto) = o;
    } else {
      const float* src; unsigned char* dst; int off;
      if (i4 < 1048576)      { src = W1; dst = w1f8; off = i4; }
      else if (i4 < 1572864) { src = W2; dst = w28;  off = i4 - 1310720; }
      else                   { src = W3; dst = w3f8; off = i4 - 1572864; }
      float4 v = *reinterpret_cast<const float4*>(src + off);
      uchar4 o;
      o.x = f2f8(v.x); o.y = f2f8(v.y); o.z = f2f8(v.z); o.w = f2f8(v.w);
      *reinterpret_cast<uchar4*>(dst + off) = o;
    }
  } else if (b < 3584){
    float (*tile)[33] = (float(*)[33])smem;
    const int idx = b - 2560;
    const int bi = idx >> 5, bj = idx & 31;
    const int tx = t & 31, ty = t >> 5;
    #pragma unroll
    for (int r = 0; r < 4; ++r){
      const int k = bj * 32 + ty + r * 8;
      const int i = bi * 32 + tx;
      tile[ty + r * 8][tx] = P[(size_t)k * 1024 + i];
    }
    __syncthreads();
    const float s = 2.0f * sinf(tptr[0]);
    #pragma unroll
    for (int r = 0; r < 4; ++r){
      const int i = bi * 32 + ty + r * 8;
      const int k = bj * 32 + tx;
      const float p = tile[tx][ty + r * 8];
      const float e = (k == 0) ? 0.0f : ((k <= 511) ? (1.0f + s) : (1.0f - s));
      PT[(size_t)i * 1024 + k] = f2b(p);
      PTeig[(size_t)i * 1024 + k] = f2b(e * p);
    }
  } else if (b < 4096){
    const int n = b - 3584;
    float a = 0.0f, bb = 0.0f;
    for (int j = t; j < 1024; j += 256) a += W1[(size_t)n * 2048 + j];
    for (int j = t; j < 1024; j += 256) bb += W1[(size_t)n * 2048 + 1024 + j];
    #pragma unroll
    for (int o = 32; o > 0; o >>= 1){ a += __shfl_down(a, o, 64); bb += __shfl_down(bb, o, 64); }
    if ((t & 63) == 0){ smem[t >> 6] = a; smem[4 + (t >> 6)] = bb; }
    __syncthreads();
    if (t == 0){
      su1[n] = smem[0] + smem[1] + smem[2] + smem[3];
      sv1[n] = smem[4] + smem[5] + smem[6] + smem[7];
    }
  } else if (b == 4096){
    float* sp  = smem;
    float* sp1 = smem + 4096;
    float* a0  = smem + 4160;
    float* a1  = smem + 4224;
    #pragma unroll
    for (int i = 0; i < 16; ++i){
      const int idx = i * 256 + t;
      const float v = softplusf(icU0[idx]);
      sp[idx] = v;
      spU0[idx] = v;
      spU0T[(idx & 63) * 64 + (idx >> 6)] = v;   // transposed copy [j][n]
    }
    if (t < 64){
      const float v1 = softplusf(icU1[t]);
      sp1[t] = v1;
      spU1[t] = v1;
      a0[t] = srelu(icb0[t]);
    }
    __syncthreads();
    {
      const int n = t >> 2, q = t & 3;
      float sAcc = 0.0f;
      #pragma unroll
      for (int j = 0; j < 16; ++j) sAcc += sp[n * 64 + q * 16 + j] * a0[q * 16 + j];
      sAcc += __shfl_down(sAcc, 2, 64);
      sAcc += __shfl_down(sAcc, 1, 64);
      if (q == 0) a1[n] = srelu(sAcc + icb1[n]);
    }
    __syncthreads();
    if (t < 64){
      float v = sp1[t] * a1[t];
      #pragma unroll
      for (int o = 32; o > 0; o >>= 1) v += __shfl_down(v, o, 64);
      if (t == 0) z0out[0] = srelu(v + icb2[0]);
    }
  } else {
    const int row = b - 4097;
    const float* srow = state + (size_t)row * 2048;
    float4 u4 = *reinterpret_cast<const float4*>(srow + t * 4);
    float4 v4 = *reinterpret_cast<const float4*>(srow + 1024 + t * 4);
    float4 wu = *reinterpret_cast<const float4*>(icW2 + t * 4);
    float4 wv = *reinterpret_cast<const float4*>(icW2 + 1024 + t * 4);
    float us[4] = {u4.x, u4.y, u4.z, u4.w};
    float vs[4] = {v4.x, v4.y, v4.z, v4.w};
    float wus[4] = {wu.x, wu.y, wu.z, wu.w};
    float wvs[4] = {wv.x, wv.y, wv.z, wv.w};
    uchar4 h8, s8u, s8v;
    unsigned char* hp = reinterpret_cast<unsigned char*>(&h8);
    unsigned char* su = reinterpret_cast<unsigned char*>(&s8u);
    unsigned char* sv = reinterpret_cast<unsigned char*>(&s8v);
    float d = 0.0f, ss = 0.0f;
    #pragma unroll
    for (int i = 0; i < 4; ++i){
      const int j = t * 4 + i;
      const float u = us[i], v = vs[i];
      stateb[(size_t)row * 2048 + j] = f2b(u);
      stateb[(size_t)row * 2048 + 1024 + j] = f2b(v);
      su[i] = f2f8(u);
      sv[i] = f2f8(v);
      hp[i] = f2f8(1.0f / (1.0f + expf(-10.0f * u)));
      d  = fmaf(wus[i], u, fmaf(wvs[i], v, d));
      ss = fmaf(u, u, fmaf(v, v, ss));
    }
    *reinterpret_cast<uchar4*>(state8 + (size_t)row * 2048 + t * 4) = s8u;
    *reinterpret_cast<uchar4*>(state8 + (size_t)row * 2048 + 1024 + t * 4) = s8v;
    *reinterpret_cast<uchar4*>(hub8 + (size_t)row * 1024 + t * 4) = h8;
    #pragma unroll
    for (int o = 32; o > 0; o >>= 1){ d += __shfl_down(d, o, 64); ss += __shfl_down(ss, o, 64); }
    if ((t & 63) == 0){ smem[t >> 6] = d; smem[4 + (t >> 6)] = ss; }
    __syncthreads();
    if (t == 0){
      rowdot[row] = smem[0] + smem[1] + smem[2] + smem[3];
      rowss[row]  = smem[4] + smem[5] + smem[6] + smem[7];
      u0a[row] = srow[0]; v0a[row] = srow[1024];
    }
  }
}

// ---------------- merged mid (Lm bf16 + z bf16, 3-buf) + h1 (fp8, 2-buf) — 48KB union, 3 blocks/CU ----------------
__global__ __launch_bounds__(512)
void gemm_midh1(const bfraw* __restrict__ pteig, const bfraw* __restrict__ pt,
                unsigned char* __restrict__ lm8,
                const bfraw* __restrict__ stateb, const bfraw* __restrict__ icwb,
                const float* __restrict__ icb0, const float* __restrict__ icb1,
                float* __restrict__ z1f, float* __restrict__ z2pre,
                const unsigned char* __restrict__ state8, const unsigned char* __restrict__ w1f8,
                const float* __restrict__ b1, unsigned char* __restrict__ h18,
                const float* __restrict__ u0a, const float* __restrict__ v0a,
                const float* __restrict__ su1, const float* __restrict__ sv1)
{
  __shared__ char ldsRaw[49152];     // 48KB union (mid: 24+24; h1: 16 A + 32 B)
  const int blk = blockIdx.x;
  const int tid = threadIdx.x;
  const int w  = tid >> 6;
  const int l  = tid & 63;
  const int lr = l & 15;
  const int q  = l >> 4;

  if (blk < 384){
    // ----- mid role (bf16, 64x64 tile, BK=64, 3-buf counted; R27-verified) -----
    bfraw* lA = (bfraw*)ldsRaw;
    bfraw* lB = (bfraw*)(ldsRaw + 24576);
    const bool isLm = (blk < 256);
    const bfraw* A; const bfraw* B; int K, bm, bn;
    if (isLm){ A = pteig; B = pt; K = 1024; bm = blk >> 4; bn = blk & 15; }
    else     { const int i = blk - 256; A = stateb; B = icwb; K = 2048; bm = i >> 1; bn = i & 1; }
    const int wr = w >> 2;
    const int wc = w & 3;
    f32x4 acc[2] = {};
    const int nt = K >> 6;
    auto stage = [&](int buf, int k0){
      const int r = tid >> 3;
      const int kc = (tid & 7) ^ (r & 7);
      gload16(A + (size_t)(bm * 64 + r) * K + k0 + kc * 8, &lA[(size_t)buf * 4096 + (size_t)(w * 64) * 8]);
      gload16(B + (size_t)(bn * 64 + r) * K + k0 + kc * 8, &lB[(size_t)buf * 4096 + (size_t)(w * 64) * 8]);
    };
    stage(0, 0);
    stage(1, 64);
    for (int t = 0; t < nt; ++t){
      const int cur = t % 3;
      if (t == nt - 1) wait_vm<0>(); else wait_vm<2>();
      block_barrier();
      short8 aF[2][2], bF[2];
      #pragma unroll
      for (int kh = 0; kh < 2; ++kh){
        const int kch = (kh * 4 + q) ^ (lr & 7);
        #pragma unroll
        for (int m = 0; m < 2; ++m){
          const int R = wr * 32 + m * 16 + lr;
          aF[kh][m] = *reinterpret_cast<const short8*>(&lA[(size_t)cur * 4096 + (size_t)R * 64 + kch * 8]);
        }
        const int R = wc * 16 + lr;
        bF[kh] = *reinterpret_cast<const short8*>(&lB[(size_t)cur * 4096 + (size_t)R * 64 + kch * 8]);
      }
      if (t + 2 < nt) stage((t + 2) % 3, (t + 2) * 64);
      #pragma unroll
      for (int kh = 0; kh < 2; ++kh)
        #pragma unroll
        for (int m = 0; m < 2; ++m)
          acc[m] = __builtin_amdgcn_mfma_f32_16x16x32_bf16(aF[kh][m], bF[kh], acc[m], 0, 0, 0);
    }
    #pragma unroll
    for (int m = 0; m < 2; ++m){
      #pragma unroll
      for (int r = 0; r < 4; ++r){
        const int row = bm * 64 + (w >> 2) * 32 + m * 16 + q * 4 + r;
        const int c64 = (w & 3) * 16 + lr;
        const float v = acc[m][r];
        if (isLm){
          lm8[(size_t)row * 1024 + bn * 64 + c64] = f2f8(v);
        } else if (bn == 0){
          z1f[(size_t)row * 64 + c64] = srelu(v + icb0[c64]);
        } else {
          z2pre[(size_t)row * 64 + c64] = v + icb1[c64];
        }
      }
    }
  } else {
    // ----- h1 role (fp8, TM=64 TN=128, BK=128; 2-buf two-barrier, R24-verified pattern) -----
    unsigned char* lA = (unsigned char*)ldsRaw;            // 2 bufs x 8192 B
    unsigned char* lB = (unsigned char*)(ldsRaw + 16384);  // 2 bufs x 16384 B
    const int i = blk - 384;
    const int bm = i >> 2;
    const int bn = i & 3;
    const int wr = w >> 2;
    const int wc = w & 3;
    constexpr int K = 2048;
    f32x4 acc[2][2] = {};
    const int nt = K >> 7;         // 16
    auto stage = [&](int buf, int k0){
      {
        const int c = tid;
        const int r = c >> 3;
        const int kc = (c & 7) ^ (r & 7);
        gload16(state8 + (size_t)(bm * 64 + r) * K + k0 + kc * 16, &lA[(size_t)buf * 8192 + (size_t)(w * 64) * 16]);
      }
      #pragma unroll
      for (int j = 0; j < 2; ++j){
        const int c = j * 512 + tid;
        const int r = c >> 3;
        const int kc = (c & 7) ^ (r & 7);
        gload16(w1f8 + (size_t)(bn * 128 + r) * K + k0 + kc * 16, &lB[(size_t)buf * 16384 + (size_t)(j * 512 + w * 64) * 16]);
      }
    };
    stage(0, 0);
    for (int t = 0; t < nt; ++t){
      const int cur = t & 1;
      if (t + 1 < nt){ stage(cur ^ 1, (t + 1) * 128); wait_vm<3>(); } else wait_vm<0>();
      block_barrier();
      long long aF[4][2], bF[4][2];
      #pragma unroll
      for (int kh = 0; kh < 4; ++kh){
        const int ko = kh * 32 + q * 8;
        const int ch = (ko >> 4) ^ (lr & 7);
        const int bo = ko & 15;
        #pragma unroll
        for (int m = 0; m < 2; ++m){
          const int R = wr * 32 + m * 16 + lr;
          aF[kh][m] = *reinterpret_cast<const long long*>(&lA[(size_t)cur * 8192 + (size_t)R * 128 + ch * 16 + bo]);
        }
        #pragma unroll
        for (int n = 0; n < 2; ++n){
          const int R = wc * 32 + n * 16 + lr;
          bF[kh][n] = *reinterpret_cast<const long long*>(&lB[(size_t)cur * 16384 + (size_t)R * 128 + ch * 16 + bo]);
        }
      }
      #pragma unroll
      for (int kh = 0; kh < 4; ++kh)
        #pragma unroll
        for (int m = 0; m < 2; ++m)
          #pragma unroll
          for (int n = 0; n < 2; ++n)
            acc[m][n] = __builtin_amdgcn_mfma_f32_16x16x32_fp8_fp8(aF[kh][m], bF[kh][n], acc[m][n], 0, 0, 0);
      block_barrier();   // reads of buf cur complete before it is restaged at t+1
    }
    #pragma unroll
    for (int m = 0; m < 2; ++m){
      #pragma unroll
      for (int n = 0; n < 2; ++n){
        #pragma unroll
        for (int r = 0; r < 4; ++r){
          const int row = bm * 64 + wr * 32 + m * 16 + q * 4 + r;
          const int col = bn * 128 + wc * 32 + n * 16 + lr;
          const float h = acc[m][n][r] - u0a[row] * su1[col] - v0a[row] * sv1[col] + b1[col];
          h18[(size_t)row * 512 + col] = f2f8(tanhf(h));
        }
      }
    }
  }
}

// ---------------- h2 = tanh(h1 @ W2^T + b2) -> fp8 (2-buf two-barrier, 48KB) ----------------
__global__ __launch_bounds__(512)
void gemm_h2(const unsigned char* __restrict__ A, const unsigned char* __restrict__ B,
             const float* __restrict__ bias, unsigned char* __restrict__ outf8)
{
  constexpr int N = 512, K = 512;
  __shared__ unsigned char lA[2][64 * 128];
  __shared__ unsigned char lB[2][128 * 128];
  const int tid = threadIdx.x;
  const int w  = tid >> 6;
  const int l  = tid & 63;
  const int wr = w >> 2;
  const int wc = w & 3;
  const int bm = blockIdx.x;
  const int bn = blockIdx.y;
  const int lr = l & 15;
  const int q  = l >> 4;
  f32x4 acc[2][2] = {};
  const int nt = K >> 7;   // 4
  auto stage = [&](int buf, int k0){
    {
      const int c = tid;
      const int r = c >> 3;
      const int kc = (c & 7) ^ (r & 7);
      gload16(A + (size_t)(bm * 64 + r) * K + k0 + kc * 16, &lA[buf][(size_t)(w * 64) * 16]);
    }
    #pragma unroll
    for (int j = 0; j < 2; ++j){
      const int c = j * 512 + tid;
      const int r = c >> 3;
      const int kc = (c & 7) ^ (r & 7);
      gload16(B + (size_t)(bn * 128 + r) * K + k0 + kc * 16, &lB[buf][(size_t)(j * 512 + w * 64) * 16]);
    }
  };
  stage(0, 0);
  for (int t = 0; t < nt; ++t){
    const int cur = t & 1;
    if (t + 1 < nt){ stage(cur ^ 1, (t + 1) * 128); wait_vm<3>(); } else wait_vm<0>();
    block_barrier();
    long long aF[4][2], bF[4][2];
    #pragma unroll
    for (int kh = 0; kh < 4; ++kh){
      const int ko = kh * 32 + q * 8;
      const int ch = (ko >> 4) ^ (lr & 7);
      const int bo = ko & 15;
      #pragma unroll
      for (int m = 0; m < 2; ++m){
        const int R = wr * 32 + m * 16 + lr;
        aF[kh][m] = *reinterpret_cast<const long long*>(&lA[cur][(size_t)R * 128 + ch * 16 + bo]);
      }
      #pragma unroll
      for (int n = 0; n < 2; ++n){
        const int R = wc * 32 + n * 16 + lr;
        bF[kh][n] = *reinterpret_cast<const long long*>(&lB[cur][(size_t)R * 128 + ch * 16 + bo]);
      }
    }
    #pragma unroll
    for (int kh = 0; kh < 4; ++kh)
      #pragma unroll
      for (int m = 0; m < 2; ++m)
        #pragma unroll
        for (int n = 0; n < 2; ++n)
          acc[m][n] = __builtin_amdgcn_mfma_f32_16x16x32_fp8_fp8(aF[kh][m], bF[kh][n], acc[m][n], 0, 0, 0);
    block_barrier();
  }
  #pragma unroll
  for (int m = 0; m < 2; ++m){
    #pragma unroll
    for (int n = 0; n < 2; ++n){
      #pragma unroll
      for (int r = 0; r < 4; ++r){
        const int row = bm * 64 + wr * 32 + m * 16 + q * 4 + r;
        const int col = bn * 128 + wc * 32 + n * 16 + lr;
        outf8[(size_t)row * N + col] = f2f8(tanhf(acc[m][n][r] + bias[col]));
      }
    }
  }
}

// ---------------- merged out + v2 (R27-verified: TM=64 single-buffer + XCD remap) ----------------
__global__ __launch_bounds__(512, 4)
void gemm_outv2(const unsigned char* __restrict__ hub8, const unsigned char* __restrict__ lm8,
                const unsigned char* __restrict__ h2b8, const unsigned char* __restrict__ w3f8,
                const bfraw* __restrict__ stateb, const float* __restrict__ b3,
                const float* __restrict__ u0a, const float* __restrict__ v0a,
                const float* __restrict__ rowdot, const float* __restrict__ rowss,
                const float* __restrict__ z1f, const float* __restrict__ z2pre,
                const float* __restrict__ spU0T, const float* __restrict__ spU1,
                const float* __restrict__ z0p, const float* __restrict__ icb2,
                float* __restrict__ out)
{
  __shared__ char ldsRaw[24576 + 512];
  const int blk = blockIdx.x;
  const int tid = threadIdx.x;

  if (blk >= 1024){
    // ----- v2 role: tiny — z2 matvec (coalesced spU0T) + combine -----
    float* z1s = (float*)ldsRaw;
    const int row = blk - 1024;
    if (tid < 64) z1s[tid] = z1f[(size_t)row * 64 + tid];
    __syncthreads();
    if (tid < 64){
      float acc2 = z2pre[(size_t)row * 64 + tid];
      #pragma unroll 8
      for (int j = 0; j < 64; ++j) acc2 += spU0T[j * 64 + tid] * z1s[j];
      float dd = spU1[tid] * srelu(acc2);
      #pragma unroll
      for (int o = 32; o > 0; o >>= 1) dd += __shfl_down(dd, o, 64);
      if (tid == 0){
        const float D = dd + rowdot[row];
        const float z3 = srelu(D + icb2[0]);
        out[(size_t)row * 2049 + 2048] = srelu(z3 - z0p[0]) + 0.001f * rowss[row];
      }
    }
    return;
  }

  // ----- gemm role: TM=64, single-buffer + XCD-aware block remap -----
  unsigned char* lA   = (unsigned char*)ldsRaw;            // 8KB (64x128)
  unsigned char* lBlo = (unsigned char*)(ldsRaw + 8192);   // 8KB
  unsigned char* lBhi = (unsigned char*)(ldsRaw + 16384);  // 8KB
  const int w  = tid >> 6;
  const int l  = tid & 63;
  const int wr = w >> 2;          // 0..1 (row halves of 64)
  const int wc = w & 3;           // 0..3
  const int xcd = blk & 7;
  const int ii  = blk >> 3;       // 0..127
  const int bm  = xcd * 8 + (ii >> 4);   // 0..63
  const int bn  = ii & 15;               // 0..15
  const int lr = l & 15;
  const int q  = l >> 4;

  const unsigned char* Au  = h2b8 + (size_t)(bm * 64) * 512;
  const unsigned char* Bwl = w3f8 + (size_t)(bn * 64) * 512;
  const unsigned char* Bwh = w3f8 + (size_t)(1024 + bn * 64) * 512;
  const unsigned char* Ah  = hub8 + (size_t)(bm * 64) * 1024;
  const unsigned char* Bl  = lm8  + (size_t)(bn * 64) * 1024;

  f32x4 acc2[2] = {};   // un lo
  f32x4 acc3[2] = {};   // un hi

  for (int t = 0; t < 4; ++t){
    const int k0 = t * 128;
    const int r = tid >> 3;
    const int kc = (tid & 7) ^ (r & 7);
    gload16(Au  + (size_t)r * 512 + k0 + kc * 16, &lA  [(size_t)(w * 64) * 16]);
    gload16(Bwl + (size_t)r * 512 + k0 + kc * 16, &lBlo[(size_t)(w * 64) * 16]);
    gload16(Bwh + (size_t)r * 512 + k0 + kc * 16, &lBhi[(size_t)(w * 64) * 16]);
    __syncthreads();
    #pragma unroll
    for (int kh = 0; kh < 4; ++kh){
      const int ko = kh * 32 + q * 8;
      const int ch = (ko >> 4) ^ (lr & 7);
      const int bo = ko & 15;
      long long aF[2], bL, bH;
      #pragma unroll
      for (int m = 0; m < 2; ++m){
        const int R = wr * 32 + m * 16 + lr;
        aF[m] = *reinterpret_cast<const long long*>(&lA[(size_t)R * 128 + ch * 16 + bo]);
      }
      const int Rb = wc * 16 + lr;
      bL = *reinterpret_cast<const long long*>(&lBlo[(size_t)Rb * 128 + ch * 16 + bo]);
      bH = *reinterpret_cast<const long long*>(&lBhi[(size_t)Rb * 128 + ch * 16 + bo]);
      #pragma unroll
      for (int m = 0; m < 2; ++m){
        acc2[m] = __builtin_amdgcn_mfma_f32_16x16x32_fp8_fp8(aF[m], bL, acc2[m], 0, 0, 0);
        acc3[m] = __builtin_amdgcn_mfma_f32_16x16x32_fp8_fp8(aF[m], bH, acc3[m], 0, 0, 0);
      }
    }
    __syncthreads();
  }

  #pragma unroll
  for (int m = 0; m < 2; ++m){
    #pragma unroll
    for (int r = 0; r < 4; ++r){
      const int row = bm * 64 + wr * 32 + m * 16 + q * 4 + r;
      const int c   = bn * 64 + wc * 16 + lr;
      const float un = acc3[m][r] + b3[1024 + c];
      const float u  = b2f(stateb[(size_t)row * 2048 + c]);
      const float vv = b2f(stateb[(size_t)row * 2048 + 1024 + c]);
      const float x  = vv - v0a[row];
      const float ux = un * x;
      const float cl = (ux < 10.0f && -10.0f < ux) ? ux : 0.0f;
      out[(size_t)row * 2049 + 1024 + c] = 0.2f * (u + 0.7f - 0.8f * vv) + cl;
    }
  }

  f32x4 acc1[2] = {};
  for (int t = 0; t < 8; ++t){
    const int k0 = t * 128;
    const int r = tid >> 3;
    const int kc = (tid & 7) ^ (r & 7);
    gload16(Ah + (size_t)r * 1024 + k0 + kc * 16, &lA  [(size_t)(w * 64) * 16]);
    gload16(Bl + (size_t)r * 1024 + k0 + kc * 16, &lBlo[(size_t)(w * 64) * 16]);
    __syncthreads();
    #pragma unroll
    for (int kh = 0; kh < 4; ++kh){
      const int ko = kh * 32 + q * 8;
      const int ch = (ko >> 4) ^ (lr & 7);
      const int bo = ko & 15;
      long long aF[2], bL;
      #pragma unroll
      for (int m = 0; m < 2; ++m){
        const int R = wr * 32 + m * 16 + lr;
        aF[m] = *reinterpret_cast<const long long*>(&lA[(size_t)R * 128 + ch * 16 + bo]);
      }
      const int Rb = wc * 16 + lr;
      bL = *reinterpret_cast<const long long*>(&lBlo[(size_t)Rb * 128 + ch * 16 + bo]);
      #pragma unroll
      for (int m = 0; m < 2; ++m){
        acc1[m] = __builtin_amdgcn_mfma_f32_16x16x32_fp8_fp8(aF[m], bL, acc1[m], 0, 0, 0);
      }
    }
    __syncthreads();
  }

  #pragma unroll
  for (int m = 0; m < 2; ++m){
    #pragma unroll
    for (int r = 0; r < 4; ++r){
      const int row = bm * 64 + wr * 32 + m * 16 + q * 4 + r;
      const int c   = bn * 64 + wc * 16 + lr;
      const float un = acc2[m][r] + b3[c];
      const float u  = b2f(stateb[(size_t)row * 2048 + c]);
      const float vv = b2f(stateb[(size_t)row * 2048 + 1024 + c]);
      const float x  = u - u0a[row];
      const float ux = un * x;
      const float cl = (ux < 10.0f && -10.0f < ux) ? ux : 0.0f;
      out[(size_t)row * 2049 + c] = acc1[m][r] + u - u * u * u * (1.0f / 3.0f) - vv + 1.0f + cl;
    }
  }
}

// ---------------- launch ----------------
extern "C" void kernel_launch(void* const* d_in, const int* in_sizes, int n_in,
                              void* d_out, int out_size, void* d_ws, size_t ws_size,
                              hipStream_t stream){
  (void)in_sizes; (void)n_in; (void)out_size; (void)ws_size;
  const float* state = (const float*)d_in[0];
  const float* tp    = (const float*)d_in[1];
  const float* P     = (const float*)d_in[2];
  const float* W1    = (const float*)d_in[3];
  const float* b1    = (const float*)d_in[4];
  const float* W2    = (const float*)d_in[5];
  const float* b2    = (const float*)d_in[6];
  const float* W3    = (const float*)d_in[7];
  const float* b3    = (const float*)d_in[8];
  const float* icW0  = (const float*)d_in[9];
  const float* icb0  = (const float*)d_in[10];
  const float* icW1  = (const float*)d_in[11];
  const float* icb1  = (const float*)d_in[12];
  const float* icW2  = (const float*)d_in[13];
  const float* icb2  = (const float*)d_in[14];
  const float* icU0  = (const float*)d_in[15];
  const float* icU1  = (const float*)d_in[16];
  float* out = (float*)d_out;
  char* ws = (char*)d_ws;

  bfraw* stateb = (bfraw*)(ws + OFF_STATEB);
  unsigned char* state8 = (unsigned char*)(ws + OFF_STATE8);
  unsigned char* hub8   = (unsigned char*)(ws + OFF_HUB);
  bfraw* pt     = (bfraw*)(ws + OFF_PT);
  bfraw* pteig  = (bfraw*)(ws + OFF_PTEIG);
  unsigned char* lm8  = (unsigned char*)(ws + OFF_LM8);
  unsigned char* w1f8 = (unsigned char*)(ws + OFF_W1F8);
  bfraw* icwb   = (bfraw*)(ws + OFF_ICWB);
  unsigned char* w28  = (unsigned char*)(ws + OFF_W28);
  unsigned char* w3f8 = (unsigned char*)(ws + OFF_W38);
  unsigned char* h18  = (unsigned char*)(ws + OFF_H18);
  unsigned char* h28  = (unsigned char*)(ws + OFF_H28);
  float* z1f    = (float*)(ws + OFF_Z1F);
  float* z2pre  = (float*)(ws + OFF_Z2PRE);
  float* spU0   = (float*)(ws + OFF_SPU0);
  float* spU0T  = (float*)(ws + OFF_SPU0T);
  float* spU1   = (float*)(ws + OFF_SPU1);
  float* z0     = (float*)(ws + OFF_Z0);
  float* su1    = (float*)(ws + OFF_SU1);
  float* sv1    = (float*)(ws + OFF_SV1);
  float* u0a    = (float*)(ws + OFF_U0);
  float* v0a    = (float*)(ws + OFF_V0);
  float* rowdot = (float*)(ws + OFF_RD);
  float* rowss  = (float*)(ws + OFF_RS);

  prep_all<<<dim3(8193), 256, 0, stream>>>(W1, icW0, icW1, W2, W3, P, tp,
      icU0, icU1, icb0, icb1, icb2, state, icW2,
      w1f8, icwb, w28, w3f8, pt, pteig, su1, sv1, spU0, spU0T, spU1, z0,
      stateb, state8, hub8, u0a, v0a, rowdot, rowss);

  // Lm + z + h1 in one dispatch (640 blocks, 48KB LDS -> 3 blocks/CU)
  gemm_midh1<<<dim3(640), 512, 0, stream>>>(pteig, pt, lm8, stateb, icwb, icb0, icb1,
      z1f, z2pre, state8, w1f8, b1, h18, u0a, v0a, su1, sv1);
  // h2 = tanh(h1 @ W2^T + b2) -> fp8
  gemm_h2<<<dim3(64, 4), 512, 0, stream>>>(h18, w28, b2, h28);
  // out[:, :2048] (1024 TM=64 gemm blocks) + V column (4096 blocks) in one dispatch
  gemm_outv2<<<dim3(5120), 512, 0, stream>>>(hub8, lm8, h28, w3f8, stateb, b3, u0a, v0a,
      rowdot, rowss, z1f, z2pre, spU0T, spU1, z0, icb2, out);
}